// Round 3
// baseline (7749.982 us; speedup 1.0000x reference)
//
#include <hip/hip_runtime.h>
#include <math.h>

#define B_ 4
#define F_ 16
#define HP_ 12
#define WP_ 16
#define N_ 192            // HP*WP
#define S_ (F_*N_)        // 3072 tokens per batch
#define ROWS (B_*S_)      // 12288
#define DIM_ 512
#define HEADS_ 8
#define DH_ 64
#define FFH_ 2048
#define PATCH_K 192
#define PI_F 3.14159265358979323846f

// ---------------- RoPE tables ----------------
__global__ void rope_tables(float* __restrict__ fsin, float* __restrict__ fcos,
                            float* __restrict__ isin, float* __restrict__ icos) {
    int tid = blockIdx.x * blockDim.x + threadIdx.x;
    int stride = gridDim.x * blockDim.x;
    // frame tables: [F_][64]; col j uses inv[j & 31] (concat, NOT interleave)
    for (int idx = tid; idx < F_ * 64; idx += stride) {
        int f = idx >> 6, j = idx & 63;
        int i = j & 31;
        float inv = powf(10000.0f, -((float)i) / 32.0f);
        float fr = (float)f * inv;
        fsin[idx] = sinf(fr);
        fcos[idx] = cosf(fr);
    }
    // image tables: [N_][64], repeat_interleave of 32 halves
    for (int idx = tid; idx < N_ * 32; idx += stride) {
        int n = idx >> 5, k = idx & 31;
        int h = n / WP_, w = n % WP_;
        float scale = exp2f((float)(k & 15) * (log2f(5.0f) / 15.0f));
        float pos = (k < 16) ? (-1.0f + 2.0f * (float)h / (float)(HP_ - 1))
                             : (-1.0f + 2.0f * (float)w / (float)(WP_ - 1));
        float val = pos * scale * PI_F;
        float sv = sinf(val), cv = cosf(val);
        isin[n * 64 + 2 * k] = sv; isin[n * 64 + 2 * k + 1] = sv;
        icos[n * 64 + 2 * k] = cv; icos[n * 64 + 2 * k + 1] = cv;
    }
}

// ---------------- patch rearrange ----------------
__global__ void rearrange_video(const float* __restrict__ video, float* __restrict__ v_pre) {
    int t = blockIdx.x * blockDim.x + threadIdx.x;
    const int total = ROWS * PATCH_K;
    if (t >= total) return;
    int col = t % PATCH_K;
    int row = t / PATCH_K;
    int c  = col % 3;
    int pp = col / 3;
    int pi = pp >> 3, pj = pp & 7;
    int n  = row % N_;
    int bf = row / N_;            // b*F + f
    int hp = n / WP_, wp = n % WP_;
    int hidx = hp * 8 + pi, widx = wp * 8 + pj;
    v_pre[t] = video[((size_t)(bf * 3 + c) * 96 + hidx) * 128 + widx];
}

// ---------------- LayerNorm: one wave per row ----------------
__global__ __launch_bounds__(64) void layernorm_k(
    const float* __restrict__ x, const float* __restrict__ g,
    const float* __restrict__ b, float* __restrict__ y) {
    int row = blockIdx.x;
    int lane = threadIdx.x;
    const float* xr = x + (size_t)row * DIM_;
    float4 v0 = *(const float4*)&xr[lane * 8];
    float4 v1 = *(const float4*)&xr[lane * 8 + 4];
    float s  = v0.x + v0.y + v0.z + v0.w + v1.x + v1.y + v1.z + v1.w;
    float sq = v0.x*v0.x + v0.y*v0.y + v0.z*v0.z + v0.w*v0.w
             + v1.x*v1.x + v1.y*v1.y + v1.z*v1.z + v1.w*v1.w;
    for (int off = 32; off; off >>= 1) { s += __shfl_xor(s, off); sq += __shfl_xor(sq, off); }
    float mu  = s * (1.0f / 512.0f);
    float var = sq * (1.0f / 512.0f) - mu * mu;
    float inv = rsqrtf(var + 1e-5f);
    float4 g0 = *(const float4*)&g[lane * 8];
    float4 g1 = *(const float4*)&g[lane * 8 + 4];
    float4 b0 = *(const float4*)&b[lane * 8];
    float4 b1 = *(const float4*)&b[lane * 8 + 4];
    float* yr = y + (size_t)row * DIM_;
    float4 o0, o1;
    o0.x = (v0.x - mu) * inv * g0.x + b0.x;
    o0.y = (v0.y - mu) * inv * g0.y + b0.y;
    o0.z = (v0.z - mu) * inv * g0.z + b0.z;
    o0.w = (v0.w - mu) * inv * g0.w + b0.w;
    o1.x = (v1.x - mu) * inv * g1.x + b1.x;
    o1.y = (v1.y - mu) * inv * g1.y + b1.y;
    o1.z = (v1.z - mu) * inv * g1.z + b1.z;
    o1.w = (v1.w - mu) * inv * g1.w + b1.w;
    *(float4*)&yr[lane * 8]     = o0;
    *(float4*)&yr[lane * 8 + 4] = o1;
}

// ---------------- fp32 GEMM: C = A[M,K] @ W[K,N] (+bias) (+residual) ----------------
// BM=128, BN=128, BK=16, 256 threads, 8x8 per thread.
// Per k-step: 64 FMA (128 VALU cyc/wave) vs 4 ds_read_b128 (~48 LDS cyc) -> VALU-bound.
template<int EPI>   // 0: C = acc (+bias if bias); 1: C += acc + bias
__global__ __launch_bounds__(256) void gemm_f32(
    const float* __restrict__ A, const float* __restrict__ W,
    const float* __restrict__ bias, float* __restrict__ C,
    int M, int N, int K) {
    const int BM = 128, BN = 128, BK = 16;
    __shared__ float As[BK][BM + 4];
    __shared__ float Bs[BK][BN];
    int bm0 = blockIdx.y * BM, bn0 = blockIdx.x * BN;
    int tid = threadIdx.x;
    int tx = tid & 15, ty = tid >> 4;
    float acc[8][8] = {};
    for (int k0 = 0; k0 < K; k0 += BK) {
        #pragma unroll
        for (int i = 0; i < 2; ++i) {           // A tile: 128x16 = 512 float4
            int f4 = i * 256 + tid;
            int row = f4 >> 2, c4 = (f4 & 3) * 4;
            float4 a = *(const float4*)&A[(size_t)(bm0 + row) * K + k0 + c4];
            As[c4 + 0][row] = a.x; As[c4 + 1][row] = a.y;
            As[c4 + 2][row] = a.z; As[c4 + 3][row] = a.w;
        }
        #pragma unroll
        for (int i = 0; i < 2; ++i) {           // B tile: 16x128 = 512 float4
            int f4 = i * 256 + tid;
            int row = f4 >> 5, c4 = (f4 & 31) * 4;
            *(float4*)&Bs[row][c4] = *(const float4*)&W[(size_t)(k0 + row) * N + bn0 + c4];
        }
        __syncthreads();
        #pragma unroll
        for (int kk = 0; kk < BK; ++kk) {
            float4 a0 = *(const float4*)&As[kk][ty * 8];
            float4 a1 = *(const float4*)&As[kk][ty * 8 + 4];
            float4 b0 = *(const float4*)&Bs[kk][tx * 8];
            float4 b1 = *(const float4*)&Bs[kk][tx * 8 + 4];
            float av[8] = {a0.x, a0.y, a0.z, a0.w, a1.x, a1.y, a1.z, a1.w};
            float bv[8] = {b0.x, b0.y, b0.z, b0.w, b1.x, b1.y, b1.z, b1.w};
            #pragma unroll
            for (int i = 0; i < 8; ++i)
                #pragma unroll
                for (int j = 0; j < 8; ++j)
                    acc[i][j] += av[i] * bv[j];
        }
        __syncthreads();
    }
    float bb[8] = {0.f,0.f,0.f,0.f,0.f,0.f,0.f,0.f};
    if (bias) {
        float4 t0 = *(const float4*)&bias[bn0 + tx * 8];
        float4 t1 = *(const float4*)&bias[bn0 + tx * 8 + 4];
        bb[0]=t0.x; bb[1]=t0.y; bb[2]=t0.z; bb[3]=t0.w;
        bb[4]=t1.x; bb[5]=t1.y; bb[6]=t1.z; bb[7]=t1.w;
    }
    #pragma unroll
    for (int i = 0; i < 8; ++i) {
        int row = bm0 + ty * 8 + i;
        float* cp = &C[(size_t)row * N + bn0 + tx * 8];
        #pragma unroll
        for (int half = 0; half < 2; ++half) {
            float4 outv;
            outv.x = acc[i][half*4+0] + bb[half*4+0];
            outv.y = acc[i][half*4+1] + bb[half*4+1];
            outv.z = acc[i][half*4+2] + bb[half*4+2];
            outv.w = acc[i][half*4+3] + bb[half*4+3];
            if (EPI == 1) {
                float4 old = *(const float4*)(cp + half*4);
                outv.x += old.x; outv.y += old.y; outv.z += old.z; outv.w += old.w;
            }
            *(float4*)(cp + half*4) = outv;
        }
    }
}

// ---------------- FF1 GEMM with fused GLU epilogue ----------------
// H2[M,2048] = (A@W[:, :2048] + b[:2048]) * gelu(A@W[:, 2048:] + b[2048:])
// BM=128, BN=64 (a and g columns each), BK=16, 256 threads, dual 8x4 acc.
__global__ __launch_bounds__(256) void gemm_glu(
    const float* __restrict__ A, const float* __restrict__ W,
    const float* __restrict__ bias, float* __restrict__ H2, int K) {
    const int BM = 128, BN = 64, BK = 16, NN = 4096, NOUT = 2048;
    __shared__ float As[BK][BM + 4];
    __shared__ float Ba[BK][BN];
    __shared__ float Bg[BK][BN];
    int bm0 = blockIdx.y * BM, bn0 = blockIdx.x * BN;
    int tid = threadIdx.x, tx = tid & 15, ty = tid >> 4;
    float acca[8][4] = {}, accg[8][4] = {};
    for (int k0 = 0; k0 < K; k0 += BK) {
        #pragma unroll
        for (int i = 0; i < 2; ++i) {           // A tile: 128x16
            int f4 = i * 256 + tid;
            int row = f4 >> 2, c4 = (f4 & 3) * 4;
            float4 a = *(const float4*)&A[(size_t)(bm0 + row) * K + k0 + c4];
            As[c4 + 0][row] = a.x; As[c4 + 1][row] = a.y;
            As[c4 + 2][row] = a.z; As[c4 + 3][row] = a.w;
        }
        {                                       // Ba/Bg tiles: 16x64 each
            int row = tid >> 4, c4 = (tid & 15) * 4;
            *(float4*)&Ba[row][c4] = *(const float4*)&W[(size_t)(k0 + row) * NN + bn0 + c4];
            *(float4*)&Bg[row][c4] = *(const float4*)&W[(size_t)(k0 + row) * NN + bn0 + NOUT + c4];
        }
        __syncthreads();
        #pragma unroll
        for (int kk = 0; kk < BK; ++kk) {
            float4 a0 = *(const float4*)&As[kk][ty * 8];
            float4 a1 = *(const float4*)&As[kk][ty * 8 + 4];
            float4 ba = *(const float4*)&Ba[kk][tx * 4];
            float4 bg = *(const float4*)&Bg[kk][tx * 4];
            float av[8]  = {a0.x, a0.y, a0.z, a0.w, a1.x, a1.y, a1.z, a1.w};
            float bav[4] = {ba.x, ba.y, ba.z, ba.w};
            float bgv[4] = {bg.x, bg.y, bg.z, bg.w};
            #pragma unroll
            for (int i = 0; i < 8; ++i)
                #pragma unroll
                for (int j = 0; j < 4; ++j) {
                    acca[i][j] += av[i] * bav[j];
                    accg[i][j] += av[i] * bgv[j];
                }
        }
        __syncthreads();
    }
    float4 bba = *(const float4*)&bias[bn0 + tx * 4];
    float4 bbg = *(const float4*)&bias[bn0 + NOUT + tx * 4];
    float ba_[4] = {bba.x, bba.y, bba.z, bba.w};
    float bg_[4] = {bbg.x, bbg.y, bbg.z, bbg.w};
    #pragma unroll
    for (int i = 0; i < 8; ++i) {
        int row = bm0 + ty * 8 + i;
        float r[4];
        #pragma unroll
        for (int j = 0; j < 4; ++j) {
            float av = acca[i][j] + ba_[j];
            float gv = accg[i][j] + bg_[j];
            float gelu = 0.5f * gv * (1.0f + erff(gv * 0.70710678118654752f));
            r[j] = av * gelu;
        }
        *(float4*)&H2[(size_t)row * NOUT + bn0 + tx * 4] = make_float4(r[0], r[1], r[2], r[3]);
    }
}

// ---------------- time attention: one wave per (b,h,n), 16x16 over frames ----------------
__global__ __launch_bounds__(64) void attn_time(
    const float* __restrict__ qkv, const float* __restrict__ fsin,
    const float* __restrict__ fcos, float* __restrict__ o) {
    int bid = blockIdx.x;               // b*HEADS_*N_ + h*N_ + n
    int n = bid % N_;
    int h = (bid / N_) % HEADS_;
    int b = bid / (N_ * HEADS_);
    int lane = threadIdx.x;             // = d
    __shared__ float qs[16][68], ks[16][68], vs[16][68], Pm[16][16];
    int parity = lane & 1;
    for (int f = 0; f < F_; ++f) {
        size_t base = (size_t)(b * S_ + f * N_ + n) * 1536 + h * 64;
        float qv = qkv[base + lane] * 0.125f;
        float kv = qkv[base + 512 + lane];
        float vv = qkv[base + 1024 + lane];
        float sn = fsin[f * 64 + lane], cs = fcos[f * 64 + lane];
        float qx = __shfl_xor(qv, 1);
        float kx = __shfl_xor(kv, 1);
        float qrot = parity ? qx : -qx;
        float krot = parity ? kx : -kx;
        qs[f][lane] = qv * cs + qrot * sn;
        ks[f][lane] = kv * cs + krot * sn;
        vs[f][lane] = vv;
    }
    __syncthreads();
    int j = lane & 15, r = lane >> 4;
    for (int rr = 0; rr < 4; ++rr) {
        int i = rr * 4 + r;
        float sacc = 0.f;
        #pragma unroll
        for (int d4 = 0; d4 < 16; ++d4) {       // rows 16B-aligned (68*4B = 272B stride)
            float4 qa = *(const float4*)&qs[i][d4 * 4];
            float4 ka = *(const float4*)&ks[j][d4 * 4];
            sacc += qa.x*ka.x + qa.y*ka.y + qa.z*ka.z + qa.w*ka.w;
        }
        float mx = sacc;
        for (int off = 8; off; off >>= 1) mx = fmaxf(mx, __shfl_xor(mx, off));
        float p = expf(sacc - mx);
        float sum = p;
        for (int off = 8; off; off >>= 1) sum += __shfl_xor(sum, off);
        Pm[i][j] = p / sum;
    }
    __syncthreads();
    for (int i = 0; i < 16; ++i) {
        float acc = 0.f;
        #pragma unroll
        for (int jj = 0; jj < 16; ++jj) acc += Pm[i][jj] * vs[jj][lane];
        o[(size_t)(b * S_ + i * N_ + n) * 512 + h * 64 + lane] = acc;
    }
}

// ---------------- spatial attention: block per (b,h,f), thread per row, flash-style ----------------
__global__ __launch_bounds__(192) void attn_space(
    const float* __restrict__ qkv, const float* __restrict__ isin,
    const float* __restrict__ icos, float* __restrict__ o) {
    int bid = blockIdx.x;               // b*HEADS_*F_ + h*F_ + f
    int f = bid % F_;
    int h = (bid / F_) % HEADS_;
    int b = bid / (F_ * HEADS_);
    int i = threadIdx.x;                // row index 0..191
    __shared__ float ks[64][64], vs[64][64];
    float q[64];
    {
        size_t base = (size_t)(b * S_ + f * N_ + i) * 1536 + h * 64;
        #pragma unroll
        for (int d2 = 0; d2 < 32; ++d2) {
            float2 t = *(const float2*)&qkv[base + 2 * d2];
            float sn = isin[i * 64 + 2 * d2], cs = icos[i * 64 + 2 * d2];
            q[2 * d2]     = (t.x * cs - t.y * sn) * 0.125f;
            q[2 * d2 + 1] = (t.y * cs + t.x * sn) * 0.125f;
        }
    }
    float m = -3.0e38f, l = 0.0f;
    float acc[64];
    #pragma unroll
    for (int d = 0; d < 64; ++d) acc[d] = 0.f;
    for (int jt = 0; jt < N_; jt += 64) {
        __syncthreads();
        for (int idx = threadIdx.x; idx < 64 * 32; idx += 192) {
            int row = idx >> 5, kc = idx & 31;
            int nj = jt + row;
            size_t base = (size_t)(b * S_ + f * N_ + nj) * 1536 + 512 + h * 64 + 2 * kc;
            float2 t = *(const float2*)&qkv[base];
            float sn = isin[nj * 64 + 2 * kc], cs = icos[nj * 64 + 2 * kc];
            ks[row][2 * kc]     = t.x * cs - t.y * sn;
            ks[row][2 * kc + 1] = t.y * cs + t.x * sn;
            float2 tv = *(const float2*)&qkv[base + 512];
            vs[row][2 * kc] = tv.x; vs[row][2 * kc + 1] = tv.y;
        }
        __syncthreads();
        for (int jg = 0; jg < 4; ++jg) {
            float s16[16];
            #pragma unroll
            for (int jj = 0; jj < 16; ++jj) {
                int jr = jg * 16 + jj;
                float s = 0.f;
                #pragma unroll
                for (int d4 = 0; d4 < 16; ++d4) {   // rows 256B stride, 16B aligned
                    float4 ka = *(const float4*)&ks[jr][d4 * 4];
                    s += q[d4*4]*ka.x + q[d4*4+1]*ka.y + q[d4*4+2]*ka.z + q[d4*4+3]*ka.w;
                }
                s16[jj] = s;
            }
            float gmax = s16[0];
            #pragma unroll
            for (int jj = 1; jj < 16; ++jj) gmax = fmaxf(gmax, s16[jj]);
            float mn = fmaxf(m, gmax);
            float corr = expf(m - mn);
            l *= corr;
            #pragma unroll
            for (int d = 0; d < 64; ++d) acc[d] *= corr;
            #pragma unroll
            for (int jj = 0; jj < 16; ++jj) {
                float p = expf(s16[jj] - mn);
                l += p;
                int jr = jg * 16 + jj;
                #pragma unroll
                for (int d4 = 0; d4 < 16; ++d4) {   // broadcast reads across threads
                    float4 vv = *(const float4*)&vs[jr][d4 * 4];
                    acc[d4*4]   += p * vv.x;
                    acc[d4*4+1] += p * vv.y;
                    acc[d4*4+2] += p * vv.z;
                    acc[d4*4+3] += p * vv.w;
                }
            }
            m = mn;
        }
    }
    float invl = 1.0f / l;
    size_t obase = (size_t)(b * S_ + f * N_ + i) * 512 + h * 64;
    #pragma unroll
    for (int d4 = 0; d4 < 16; ++d4) {
        float4 w;
        w.x = acc[d4 * 4 + 0] * invl;
        w.y = acc[d4 * 4 + 1] * invl;
        w.z = acc[d4 * 4 + 2] * invl;
        w.w = acc[d4 * 4 + 3] * invl;
        *(float4*)&o[obase + d4 * 4] = w;
    }
}

extern "C" void kernel_launch(void* const* d_in, const int* in_sizes, int n_in,
                              void* d_out, int out_size, void* d_ws, size_t ws_size,
                              hipStream_t stream) {
    (void)in_sizes; (void)n_in; (void)out_size;
    const float* video   = (const float*)d_in[0];
    const float* patch_w = (const float*)d_in[1];
    const float* patch_b = (const float*)d_in[2];
    const float* ln_t_g  = (const float*)d_in[3];
    const float* ln_t_b  = (const float*)d_in[4];
    const float* ln_s_g  = (const float*)d_in[5];
    const float* ln_s_b  = (const float*)d_in[6];
    const float* ln_f_g  = (const float*)d_in[7];
    const float* ln_f_b  = (const float*)d_in[8];
    const float* qkv_t   = (const float*)d_in[9];
    const float* out_t_w = (const float*)d_in[10];
    const float* out_t_b = (const float*)d_in[11];
    const float* qkv_s   = (const float*)d_in[12];
    const float* out_s_w = (const float*)d_in[13];
    const float* out_s_b = (const float*)d_in[14];
    const float* ff_w1   = (const float*)d_in[15];
    const float* ff_b1   = (const float*)d_in[16];
    const float* ff_w2   = (const float*)d_in[17];
    const float* ff_b2   = (const float*)d_in[18];

    float* x  = (float*)d_out;                       // [12288][512] residual stream
    float* ws = (float*)d_ws;

    // Workspace: big (v_pre/qkv/h2 shared, never simultaneously live) + yo (LN y / attn o) + tables.
    //   full layout : big = ROWS*2048 (h2 whole batch)  -> total 125.9 MB
    //   small layout: big = ROWS*1536 (qkv; h2 halved)  -> total 100.8 MB
    const size_t yoN  = (size_t)ROWS * DIM_;
    const size_t tabN = (size_t)F_ * 64 * 2 + (size_t)N_ * 64 * 2;
    const size_t fullNeed = ((size_t)ROWS * 2048 + yoN + tabN) * sizeof(float);
    const bool full = ws_size >= fullNeed;
    const size_t bigN = full ? (size_t)ROWS * 2048 : (size_t)ROWS * 1536;

    float* big  = ws;
    float* yo   = big + bigN;
    float* fsin = yo + yoN;
    float* fcos = fsin + F_ * 64;
    float* isin = fcos + F_ * 64;
    float* icos = isin + N_ * 64;
    float* v_pre = big;
    float* qkv   = big;
    float* h2    = big;
    float* y     = yo;
    float* o     = yo;   // alias: y dead before o written

    rope_tables<<<2, 256, 0, stream>>>(fsin, fcos, isin, icos);
    rearrange_video<<<(ROWS * PATCH_K + 255) / 256, 256, 0, stream>>>(video, v_pre);
    gemm_f32<0><<<dim3(DIM_ / 128, ROWS / 128), 256, 0, stream>>>(
        v_pre, patch_w, patch_b, x, ROWS, DIM_, PATCH_K);

    for (int l = 0; l < 4; ++l) {
        // ---- time attention ----
        layernorm_k<<<ROWS, 64, 0, stream>>>(x, ln_t_g + l * DIM_, ln_t_b + l * DIM_, y);
        gemm_f32<0><<<dim3(1536 / 128, ROWS / 128), 256, 0, stream>>>(
            y, qkv_t + (size_t)l * DIM_ * 1536, nullptr, qkv, ROWS, 1536, DIM_);
        attn_time<<<B_ * HEADS_ * N_, 64, 0, stream>>>(qkv, fsin, fcos, o);
        gemm_f32<1><<<dim3(DIM_ / 128, ROWS / 128), 256, 0, stream>>>(
            o, out_t_w + (size_t)l * DIM_ * DIM_, out_t_b + l * DIM_, x, ROWS, DIM_, DIM_);
        // ---- spatial attention ----
        layernorm_k<<<ROWS, 64, 0, stream>>>(x, ln_s_g + l * DIM_, ln_s_b + l * DIM_, y);
        gemm_f32<0><<<dim3(1536 / 128, ROWS / 128), 256, 0, stream>>>(
            y, qkv_s + (size_t)l * DIM_ * 1536, nullptr, qkv, ROWS, 1536, DIM_);
        attn_space<<<B_ * HEADS_ * F_, 192, 0, stream>>>(qkv, isin, icos, o);
        gemm_f32<1><<<dim3(DIM_ / 128, ROWS / 128), 256, 0, stream>>>(
            o, out_s_w + (size_t)l * DIM_ * DIM_, out_s_b + l * DIM_, x, ROWS, DIM_, DIM_);
        // ---- FF with fused GLU ----
        layernorm_k<<<ROWS, 64, 0, stream>>>(x, ln_f_g + l * DIM_, ln_f_b + l * DIM_, y);
        if (full) {
            gemm_glu<<<dim3(FFH_ / 64, ROWS / 128), 256, 0, stream>>>(
                y, ff_w1 + (size_t)l * DIM_ * 2 * FFH_, ff_b1 + l * 2 * FFH_, h2, DIM_);
            gemm_f32<1><<<dim3(DIM_ / 128, ROWS / 128), 256, 0, stream>>>(
                h2, ff_w2 + (size_t)l * FFH_ * DIM_, ff_b2 + l * DIM_, x, ROWS, DIM_, FFH_);
        } else {
            const int MH = ROWS / 2;                 // 6144 rows per half
            for (int half = 0; half < 2; ++half) {
                const float* yh = y + (size_t)half * MH * DIM_;
                float*       xh = x + (size_t)half * MH * DIM_;
                gemm_glu<<<dim3(FFH_ / 64, MH / 128), 256, 0, stream>>>(
                    yh, ff_w1 + (size_t)l * DIM_ * 2 * FFH_, ff_b1 + l * 2 * FFH_, h2, DIM_);
                gemm_f32<1><<<dim3(DIM_ / 128, MH / 128), 256, 0, stream>>>(
                    h2, ff_w2 + (size_t)l * FFH_ * DIM_, ff_b2 + l * DIM_, xh, MH, DIM_, FFH_);
            }
        }
    }
}

// Round 4
// 3800.068 us; speedup vs baseline: 2.0394x; 2.0394x over previous
//
#include <hip/hip_runtime.h>
#include <math.h>

#define B_ 4
#define F_ 16
#define HP_ 12
#define WP_ 16
#define N_ 192            // HP*WP
#define S_ (F_*N_)        // 3072 tokens per batch
#define ROWS (B_*S_)      // 12288
#define DIM_ 512
#define HEADS_ 8
#define DH_ 64
#define FFH_ 2048
#define PATCH_K 192
#define PI_F 3.14159265358979323846f

typedef unsigned short u16;
typedef __attribute__((ext_vector_type(8))) short bf16x8;
typedef __attribute__((ext_vector_type(4))) float f32x4;

__device__ __forceinline__ u16 bf16_rne(float f) {
    unsigned int u = __float_as_uint(f);
    u += 0x7FFFu + ((u >> 16) & 1u);
    return (u16)(u >> 16);
}
__device__ __forceinline__ float bf16_f32(u16 h) {
    return __uint_as_float(((unsigned int)h) << 16);
}

// ---------------- RoPE tables ----------------
__global__ void rope_tables(float* __restrict__ fsin, float* __restrict__ fcos,
                            float* __restrict__ isin, float* __restrict__ icos) {
    int tid = blockIdx.x * blockDim.x + threadIdx.x;
    int stride = gridDim.x * blockDim.x;
    for (int idx = tid; idx < F_ * 64; idx += stride) {
        int f = idx >> 6, j = idx & 63;
        int i = j & 31;
        float inv = powf(10000.0f, -((float)i) / 32.0f);
        float fr = (float)f * inv;
        fsin[idx] = sinf(fr);
        fcos[idx] = cosf(fr);
    }
    for (int idx = tid; idx < N_ * 32; idx += stride) {
        int n = idx >> 5, k = idx & 31;
        int h = n / WP_, w = n % WP_;
        float scale = exp2f((float)(k & 15) * (log2f(5.0f) / 15.0f));
        float pos = (k < 16) ? (-1.0f + 2.0f * (float)h / (float)(HP_ - 1))
                             : (-1.0f + 2.0f * (float)w / (float)(WP_ - 1));
        float val = pos * scale * PI_F;
        float sv = sinf(val), cv = cosf(val);
        isin[n * 64 + 2 * k] = sv; isin[n * 64 + 2 * k + 1] = sv;
        icos[n * 64 + 2 * k] = cv; icos[n * 64 + 2 * k + 1] = cv;
    }
}

// ---------------- patch rearrange -> bf16 hi/lo planes ----------------
__global__ void rearrange_video_p(const float* __restrict__ video,
                                  u16* __restrict__ Vh, u16* __restrict__ Vl) {
    int t = blockIdx.x * blockDim.x + threadIdx.x;
    const int total = ROWS * PATCH_K;
    if (t >= total) return;
    int col = t % PATCH_K;
    int row = t / PATCH_K;
    int c  = col % 3;
    int pp = col / 3;
    int pi = pp >> 3, pj = pp & 7;
    int n  = row % N_;
    int bf = row / N_;
    int hp = n / WP_, wp = n % WP_;
    int hidx = hp * 8 + pi, widx = wp * 8 + pj;
    float f = video[((size_t)(bf * 3 + c) * 96 + hidx) * 128 + widx];
    u16 h = bf16_rne(f);
    Vh[t] = h;
    Vl[t] = bf16_rne(f - bf16_f32(h));
}

// ---------------- weight transpose + split: W[K][N] f32 -> Wt_hi/lo [N][K] bf16 ----------------
__global__ __launch_bounds__(256) void convert_wt(
    const float* __restrict__ W, u16* __restrict__ Wh, u16* __restrict__ Wl,
    int K, int N) {
    __shared__ float tile[32][33];
    int nb = blockIdx.x * 32, kb = blockIdx.y * 32;
    int tx = threadIdx.x & 31, ty = threadIdx.x >> 5;   // ty 0..7
    #pragma unroll
    for (int i = 0; i < 32; i += 8)
        tile[ty + i][tx] = W[(size_t)(kb + ty + i) * N + nb + tx];
    __syncthreads();
    #pragma unroll
    for (int i = 0; i < 32; i += 8) {
        int n = nb + ty + i, k = kb + tx;
        float f = tile[tx][ty + i];
        u16 h = bf16_rne(f);
        Wh[(size_t)n * K + k] = h;
        Wl[(size_t)n * K + k] = bf16_rne(f - bf16_f32(h));
    }
}

// ---------------- LayerNorm -> bf16 hi/lo planes ----------------
__global__ __launch_bounds__(64) void layernorm_p(
    const float* __restrict__ x, const float* __restrict__ g,
    const float* __restrict__ b, u16* __restrict__ Yh, u16* __restrict__ Yl) {
    int row = blockIdx.x;
    int lane = threadIdx.x;
    const float* xr = x + (size_t)row * DIM_;
    float4 v0 = *(const float4*)&xr[lane * 8];
    float4 v1 = *(const float4*)&xr[lane * 8 + 4];
    float s  = v0.x + v0.y + v0.z + v0.w + v1.x + v1.y + v1.z + v1.w;
    float sq = v0.x*v0.x + v0.y*v0.y + v0.z*v0.z + v0.w*v0.w
             + v1.x*v1.x + v1.y*v1.y + v1.z*v1.z + v1.w*v1.w;
    for (int off = 32; off; off >>= 1) { s += __shfl_xor(s, off); sq += __shfl_xor(sq, off); }
    float mu  = s * (1.0f / 512.0f);
    float var = sq * (1.0f / 512.0f) - mu * mu;
    float inv = rsqrtf(var + 1e-5f);
    float4 g0 = *(const float4*)&g[lane * 8];
    float4 g1 = *(const float4*)&g[lane * 8 + 4];
    float4 b0 = *(const float4*)&b[lane * 8];
    float4 b1 = *(const float4*)&b[lane * 8 + 4];
    float o[8];
    o[0] = (v0.x - mu) * inv * g0.x + b0.x;
    o[1] = (v0.y - mu) * inv * g0.y + b0.y;
    o[2] = (v0.z - mu) * inv * g0.z + b0.z;
    o[3] = (v0.w - mu) * inv * g0.w + b0.w;
    o[4] = (v1.x - mu) * inv * g1.x + b1.x;
    o[5] = (v1.y - mu) * inv * g1.y + b1.y;
    o[6] = (v1.z - mu) * inv * g1.z + b1.z;
    o[7] = (v1.w - mu) * inv * g1.w + b1.w;
    size_t ro = (size_t)row * DIM_ + lane * 8;
    ushort4 h0, h1, l0, l1;
    h0.x = bf16_rne(o[0]); l0.x = bf16_rne(o[0] - bf16_f32(h0.x));
    h0.y = bf16_rne(o[1]); l0.y = bf16_rne(o[1] - bf16_f32(h0.y));
    h0.z = bf16_rne(o[2]); l0.z = bf16_rne(o[2] - bf16_f32(h0.z));
    h0.w = bf16_rne(o[3]); l0.w = bf16_rne(o[3] - bf16_f32(h0.w));
    h1.x = bf16_rne(o[4]); l1.x = bf16_rne(o[4] - bf16_f32(h1.x));
    h1.y = bf16_rne(o[5]); l1.y = bf16_rne(o[5] - bf16_f32(h1.y));
    h1.z = bf16_rne(o[6]); l1.z = bf16_rne(o[6] - bf16_f32(h1.z));
    h1.w = bf16_rne(o[7]); l1.w = bf16_rne(o[7] - bf16_f32(h1.w));
    *(ushort4*)&Yh[ro]     = h0;
    *(ushort4*)&Yh[ro + 4] = h1;
    *(ushort4*)&Yl[ro]     = l0;
    *(ushort4*)&Yl[ro + 4] = l1;
}

// ---------------- split-bf16 MFMA GEMM: C = A@W^T(+bias)(+residual) ----------------
// A planes [M][K] bf16 hi/lo; W planes [N][K] bf16 hi/lo (transposed). 128x128 tile,
// BK=32, 4 waves 2x2, each wave 64x64 (4x4 frags of 16x16x32). 3 MFMAs per frag-pair.
template<int EPI>   // 0: C = acc(+bias); 1: C += acc + bias
__global__ __launch_bounds__(256) void gemm_mfma3(
    const u16* __restrict__ Ah, const u16* __restrict__ Al,
    const u16* __restrict__ Wh, const u16* __restrict__ Wl,
    const float* __restrict__ bias, float* __restrict__ C,
    int M, int N, int K) {
    __shared__ u16 As[2][128 * 40];
    __shared__ u16 Ws[2][128 * 40];
    const int bm0 = blockIdx.y * 128, bn0 = blockIdx.x * 128;
    const int tid = threadIdx.x, lane = tid & 63, wid = tid >> 6;
    const int wm = (wid >> 1) * 64, wn = (wid & 1) * 64;
    const int fr = lane & 15, kg = (lane >> 4) * 8;
    f32x4 acc[4][4] = {};
    for (int k0 = 0; k0 < K; k0 += 32) {
        #pragma unroll
        for (int it = 0; it < 2; ++it) {
            int cc = it * 256 + tid;            // 0..511
            int row = cc >> 2, kc = (cc & 3) * 8;
            size_t ga = (size_t)(bm0 + row) * K + k0 + kc;
            size_t gw = (size_t)(bn0 + row) * K + k0 + kc;
            *(uint4*)&As[0][row * 40 + kc] = *(const uint4*)&Ah[ga];
            *(uint4*)&As[1][row * 40 + kc] = *(const uint4*)&Al[ga];
            *(uint4*)&Ws[0][row * 40 + kc] = *(const uint4*)&Wh[gw];
            *(uint4*)&Ws[1][row * 40 + kc] = *(const uint4*)&Wl[gw];
        }
        __syncthreads();
        bf16x8 ah[4], al[4], bh[4], bl[4];
        #pragma unroll
        for (int i = 0; i < 4; ++i) {
            ah[i] = *(const bf16x8*)&As[0][(wm + i * 16 + fr) * 40 + kg];
            al[i] = *(const bf16x8*)&As[1][(wm + i * 16 + fr) * 40 + kg];
            bh[i] = *(const bf16x8*)&Ws[0][(wn + i * 16 + fr) * 40 + kg];
            bl[i] = *(const bf16x8*)&Ws[1][(wn + i * 16 + fr) * 40 + kg];
        }
        #pragma unroll
        for (int i = 0; i < 4; ++i)
            #pragma unroll
            for (int j = 0; j < 4; ++j) {
                acc[i][j] = __builtin_amdgcn_mfma_f32_16x16x32_bf16(ah[i], bh[j], acc[i][j], 0, 0, 0);
                acc[i][j] = __builtin_amdgcn_mfma_f32_16x16x32_bf16(ah[i], bl[j], acc[i][j], 0, 0, 0);
                acc[i][j] = __builtin_amdgcn_mfma_f32_16x16x32_bf16(al[i], bh[j], acc[i][j], 0, 0, 0);
            }
        __syncthreads();
    }
    const int r0 = (lane >> 4) * 4;
    #pragma unroll
    for (int i = 0; i < 4; ++i)
        #pragma unroll
        for (int j = 0; j < 4; ++j) {
            int col = bn0 + wn + j * 16 + fr;
            float bb = bias ? bias[col] : 0.0f;
            #pragma unroll
            for (int r = 0; r < 4; ++r) {
                int row = bm0 + wm + i * 16 + r0 + r;
                float v = acc[i][j][r] + bb;
                size_t off = (size_t)row * N + col;
                if (EPI == 1) v += C[off];
                C[off] = v;
            }
        }
}

// ---------------- split-bf16 MFMA GEMM with fused GLU epilogue ----------------
// H2[M][2048] = (A@W1t[0:2048]^T + b[:2048]) * gelu(A@W1t[2048:]^T + b[2048:])
// out as bf16 hi/lo planes. BM=128, BN_out=64, K=512. W LDS rows 0..63 = a-cols, 64..127 = g-cols.
__global__ __launch_bounds__(256) void gemm_glu3(
    const u16* __restrict__ Ah, const u16* __restrict__ Al,
    const u16* __restrict__ Wh, const u16* __restrict__ Wl,
    const float* __restrict__ bias, u16* __restrict__ Hh, u16* __restrict__ Hl) {
    const int K = DIM_;
    __shared__ u16 As[2][128 * 40];
    __shared__ u16 Ws[2][128 * 40];
    const int bm0 = blockIdx.y * 128, bn0 = blockIdx.x * 64;
    const int tid = threadIdx.x, lane = tid & 63, wid = tid >> 6;
    const int wm = (wid >> 1) * 64, wn2 = (wid & 1) * 32;
    const int fr = lane & 15, kg = (lane >> 4) * 8;
    f32x4 acca[4][2] = {}, accg[4][2] = {};
    for (int k0 = 0; k0 < K; k0 += 32) {
        #pragma unroll
        for (int it = 0; it < 2; ++it) {
            int cc = it * 256 + tid;
            int row = cc >> 2, kc = (cc & 3) * 8;
            size_t ga = (size_t)(bm0 + row) * K + k0 + kc;
            int ng = (row < 64) ? (bn0 + row) : (FFH_ + bn0 + row - 64);
            size_t gw = (size_t)ng * K + k0 + kc;
            *(uint4*)&As[0][row * 40 + kc] = *(const uint4*)&Ah[ga];
            *(uint4*)&As[1][row * 40 + kc] = *(const uint4*)&Al[ga];
            *(uint4*)&Ws[0][row * 40 + kc] = *(const uint4*)&Wh[gw];
            *(uint4*)&Ws[1][row * 40 + kc] = *(const uint4*)&Wl[gw];
        }
        __syncthreads();
        bf16x8 ah[4], al[4], bah[2], bal[2], bgh[2], bgl[2];
        #pragma unroll
        for (int i = 0; i < 4; ++i) {
            ah[i] = *(const bf16x8*)&As[0][(wm + i * 16 + fr) * 40 + kg];
            al[i] = *(const bf16x8*)&As[1][(wm + i * 16 + fr) * 40 + kg];
        }
        #pragma unroll
        for (int j = 0; j < 2; ++j) {
            bah[j] = *(const bf16x8*)&Ws[0][(wn2 + j * 16 + fr) * 40 + kg];
            bal[j] = *(const bf16x8*)&Ws[1][(wn2 + j * 16 + fr) * 40 + kg];
            bgh[j] = *(const bf16x8*)&Ws[0][(64 + wn2 + j * 16 + fr) * 40 + kg];
            bgl[j] = *(const bf16x8*)&Ws[1][(64 + wn2 + j * 16 + fr) * 40 + kg];
        }
        #pragma unroll
        for (int i = 0; i < 4; ++i)
            #pragma unroll
            for (int j = 0; j < 2; ++j) {
                acca[i][j] = __builtin_amdgcn_mfma_f32_16x16x32_bf16(ah[i], bah[j], acca[i][j], 0, 0, 0);
                acca[i][j] = __builtin_amdgcn_mfma_f32_16x16x32_bf16(ah[i], bal[j], acca[i][j], 0, 0, 0);
                acca[i][j] = __builtin_amdgcn_mfma_f32_16x16x32_bf16(al[i], bah[j], acca[i][j], 0, 0, 0);
                accg[i][j] = __builtin_amdgcn_mfma_f32_16x16x32_bf16(ah[i], bgh[j], accg[i][j], 0, 0, 0);
                accg[i][j] = __builtin_amdgcn_mfma_f32_16x16x32_bf16(ah[i], bgl[j], accg[i][j], 0, 0, 0);
                accg[i][j] = __builtin_amdgcn_mfma_f32_16x16x32_bf16(al[i], bgh[j], accg[i][j], 0, 0, 0);
            }
        __syncthreads();
    }
    const int r0 = (lane >> 4) * 4;
    #pragma unroll
    for (int i = 0; i < 4; ++i)
        #pragma unroll
        for (int j = 0; j < 2; ++j) {
            int col = bn0 + wn2 + j * 16 + fr;
            float ba = bias[col], bg = bias[FFH_ + col];
            #pragma unroll
            for (int r = 0; r < 4; ++r) {
                int row = bm0 + wm + i * 16 + r0 + r;
                float av = acca[i][j][r] + ba;
                float gv = accg[i][j][r] + bg;
                float gl = 0.5f * gv * (1.0f + erff(gv * 0.70710678118654752f));
                float v = av * gl;
                u16 h = bf16_rne(v);
                size_t off = (size_t)row * FFH_ + col;
                Hh[off] = h;
                Hl[off] = bf16_rne(v - bf16_f32(h));
            }
        }
}

// ---------------- time attention: one wave per (b,h,n); writes o as bf16 pairs ----------------
__global__ __launch_bounds__(64) void attn_time(
    const float* __restrict__ qkv, const float* __restrict__ fsin,
    const float* __restrict__ fcos, u16* __restrict__ Oh, u16* __restrict__ Ol) {
    int bid = blockIdx.x;               // b*HEADS_*N_ + h*N_ + n
    int n = bid % N_;
    int h = (bid / N_) % HEADS_;
    int b = bid / (N_ * HEADS_);
    int lane = threadIdx.x;             // = d
    __shared__ float qs[16][68], ks[16][68], vs[16][68], Pm[16][16];
    int parity = lane & 1;
    for (int f = 0; f < F_; ++f) {
        size_t base = (size_t)(b * S_ + f * N_ + n) * 1536 + h * 64;
        float qv = qkv[base + lane] * 0.125f;
        float kv = qkv[base + 512 + lane];
        float vv = qkv[base + 1024 + lane];
        float sn = fsin[f * 64 + lane], cs = fcos[f * 64 + lane];
        float qx = __shfl_xor(qv, 1);
        float kx = __shfl_xor(kv, 1);
        float qrot = parity ? qx : -qx;
        float krot = parity ? kx : -kx;
        qs[f][lane] = qv * cs + qrot * sn;
        ks[f][lane] = kv * cs + krot * sn;
        vs[f][lane] = vv;
    }
    __syncthreads();
    int j = lane & 15, r = lane >> 4;
    for (int rr = 0; rr < 4; ++rr) {
        int i = rr * 4 + r;
        float sacc = 0.f;
        #pragma unroll
        for (int d4 = 0; d4 < 16; ++d4) {
            float4 qa = *(const float4*)&qs[i][d4 * 4];
            float4 ka = *(const float4*)&ks[j][d4 * 4];
            sacc += qa.x*ka.x + qa.y*ka.y + qa.z*ka.z + qa.w*ka.w;
        }
        float mx = sacc;
        for (int off = 8; off; off >>= 1) mx = fmaxf(mx, __shfl_xor(mx, off));
        float p = expf(sacc - mx);
        float sum = p;
        for (int off = 8; off; off >>= 1) sum += __shfl_xor(sum, off);
        Pm[i][j] = p / sum;
    }
    __syncthreads();
    for (int i = 0; i < 16; ++i) {
        float acc = 0.f;
        #pragma unroll
        for (int jj = 0; jj < 16; ++jj) acc += Pm[i][jj] * vs[jj][lane];
        size_t ob = (size_t)(b * S_ + i * N_ + n) * 512 + h * 64 + lane;
        u16 hh = bf16_rne(acc);
        Oh[ob] = hh;
        Ol[ob] = bf16_rne(acc - bf16_f32(hh));
    }
}

// ---------------- spatial attention: block per (b,h,f); writes o pairs via LDS repack ----------------
__global__ __launch_bounds__(192) void attn_space(
    const float* __restrict__ qkv, const float* __restrict__ isin,
    const float* __restrict__ icos, u16* __restrict__ Oh, u16* __restrict__ Ol) {
    int bid = blockIdx.x;               // b*HEADS_*F_ + h*F_ + f
    int f = bid % F_;
    int h = (bid / F_) % HEADS_;
    int b = bid / (F_ * HEADS_);
    int i = threadIdx.x;                // row 0..191
    __shared__ float smempool[2 * 64 * 64];     // ks | vs ; reused as u16 repack buf
    float (*ks)[64] = (float (*)[64])smempool;
    float (*vs)[64] = (float (*)[64])(smempool + 64 * 64);
    float q[64];
    {
        size_t base = (size_t)(b * S_ + f * N_ + i) * 1536 + h * 64;
        #pragma unroll
        for (int d2 = 0; d2 < 32; ++d2) {
            float2 t = *(const float2*)&qkv[base + 2 * d2];
            float sn = isin[i * 64 + 2 * d2], cs = icos[i * 64 + 2 * d2];
            q[2 * d2]     = (t.x * cs - t.y * sn) * 0.125f;
            q[2 * d2 + 1] = (t.y * cs + t.x * sn) * 0.125f;
        }
    }
    float m = -3.0e38f, l = 0.0f;
    float acc[64];
    #pragma unroll
    for (int d = 0; d < 64; ++d) acc[d] = 0.f;
    for (int jt = 0; jt < N_; jt += 64) {
        __syncthreads();
        for (int idx = threadIdx.x; idx < 64 * 32; idx += 192) {
            int row = idx >> 5, kc = idx & 31;
            int nj = jt + row;
            size_t base = (size_t)(b * S_ + f * N_ + nj) * 1536 + 512 + h * 64 + 2 * kc;
            float2 t = *(const float2*)&qkv[base];
            float sn = isin[nj * 64 + 2 * kc], cs = icos[nj * 64 + 2 * kc];
            ks[row][2 * kc]     = t.x * cs - t.y * sn;
            ks[row][2 * kc + 1] = t.y * cs + t.x * sn;
            float2 tv = *(const float2*)&qkv[base + 512];
            vs[row][2 * kc] = tv.x; vs[row][2 * kc + 1] = tv.y;
        }
        __syncthreads();
        for (int jg = 0; jg < 4; ++jg) {
            float s16[16];
            #pragma unroll
            for (int jj = 0; jj < 16; ++jj) {
                int jr = jg * 16 + jj;
                float s = 0.f;
                #pragma unroll
                for (int d4 = 0; d4 < 16; ++d4) {
                    float4 ka = *(const float4*)&ks[jr][d4 * 4];
                    s += q[d4*4]*ka.x + q[d4*4+1]*ka.y + q[d4*4+2]*ka.z + q[d4*4+3]*ka.w;
                }
                s16[jj] = s;
            }
            float gmax = s16[0];
            #pragma unroll
            for (int jj = 1; jj < 16; ++jj) gmax = fmaxf(gmax, s16[jj]);
            float mn = fmaxf(m, gmax);
            float corr = expf(m - mn);
            l *= corr;
            #pragma unroll
            for (int d = 0; d < 64; ++d) acc[d] *= corr;
            #pragma unroll
            for (int jj = 0; jj < 16; ++jj) {
                float p = expf(s16[jj] - mn);
                l += p;
                int jr = jg * 16 + jj;
                #pragma unroll
                for (int d4 = 0; d4 < 16; ++d4) {
                    float4 vv = *(const float4*)&vs[jr][d4 * 4];
                    acc[d4*4]   += p * vv.x;
                    acc[d4*4+1] += p * vv.y;
                    acc[d4*4+2] += p * vv.z;
                    acc[d4*4+3] += p * vv.w;
                }
            }
            m = mn;
        }
    }
    float invl = 1.0f / l;
    #pragma unroll
    for (int d = 0; d < 64; ++d) acc[d] *= invl;
    // repack via LDS for coalesced u16 stores: buf [192][68]
    u16* sm = (u16*)smempool;
    __syncthreads();
    #pragma unroll
    for (int d = 0; d < 64; ++d) sm[i * 68 + d] = bf16_rne(acc[d]);
    __syncthreads();
    for (int idx = threadIdx.x; idx < 192 * 16; idx += 192) {
        int row = idx >> 4, c = idx & 15;
        size_t ob = (size_t)(b * S_ + f * N_ + row) * 512 + h * 64 + c * 4;
        *(ushort4*)&Oh[ob] = *(const ushort4*)&sm[row * 68 + c * 4];
    }
    __syncthreads();
    #pragma unroll
    for (int d = 0; d < 64; ++d)
        sm[i * 68 + d] = bf16_rne(acc[d] - bf16_f32(bf16_rne(acc[d])));
    __syncthreads();
    for (int idx = threadIdx.x; idx < 192 * 16; idx += 192) {
        int row = idx >> 4, c = idx & 15;
        size_t ob = (size_t)(b * S_ + f * N_ + row) * 512 + h * 64 + c * 4;
        *(ushort4*)&Ol[ob] = *(const ushort4*)&sm[row * 68 + c * 4];
    }
}

extern "C" void kernel_launch(void* const* d_in, const int* in_sizes, int n_in,
                              void* d_out, int out_size, void* d_ws, size_t ws_size,
                              hipStream_t stream) {
    (void)in_sizes; (void)n_in; (void)out_size; (void)ws_size;
    const float* video   = (const float*)d_in[0];
    const float* patch_w = (const float*)d_in[1];
    const float* patch_b = (const float*)d_in[2];
    const float* ln_t_g  = (const float*)d_in[3];
    const float* ln_t_b  = (const float*)d_in[4];
    const float* ln_s_g  = (const float*)d_in[5];
    const float* ln_s_b  = (const float*)d_in[6];
    const float* ln_f_g  = (const float*)d_in[7];
    const float* ln_f_b  = (const float*)d_in[8];
    const float* qkv_t   = (const float*)d_in[9];
    const float* out_t_w = (const float*)d_in[10];
    const float* out_t_b = (const float*)d_in[11];
    const float* qkv_s   = (const float*)d_in[12];
    const float* out_s_w = (const float*)d_in[13];
    const float* out_s_b = (const float*)d_in[14];
    const float* ff_w1   = (const float*)d_in[15];
    const float* ff_b1   = (const float*)d_in[16];
    const float* ff_w2   = (const float*)d_in[17];
    const float* ff_b2   = (const float*)d_in[18];

    float* x = (float*)d_out;                   // [12288][512] residual stream

    // ---- workspace layout (~104.5 MB) ----
    u16* wqt_h = (u16*)d_ws;                    // qkv_t^T pair [1536][512]
    u16* wqt_l = wqt_h + 1536 * 512;
    u16* wot_h = wqt_l + 1536 * 512;            // out_t^T pair [512][512]
    u16* wot_l = wot_h + 512 * 512;
    u16* wqs_h = wot_l + 512 * 512;
    u16* wqs_l = wqs_h + 1536 * 512;
    u16* wos_h = wqs_l + 1536 * 512;
    u16* wos_l = wos_h + 512 * 512;
    u16* wpt_h = wos_l + 512 * 512;             // patch_w^T pair [512][192]
    u16* wpt_l = wpt_h + 512 * PATCH_K;
    u16* y_h   = wpt_l + 512 * PATCH_K;         // activation pair [12288][512]; o aliases y
    u16* y_l   = y_h + (size_t)ROWS * DIM_;
    float* big2 = (float*)(y_l + (size_t)ROWS * DIM_);  // 75.5 MB multi-use region
    float* qkv  = big2;                                  // [12288][1536] fp32
    u16* vp_h = (u16*)big2;                              // patch pre pair [12288][192]
    u16* vp_l = vp_h + (size_t)ROWS * PATCH_K;
    u16* h2_h = (u16*)big2;                              // FF phase: [6144][2048] pair
    u16* h2_l = h2_h + (size_t)(ROWS / 2) * FFH_;
    u16* f1t_h = h2_l + (size_t)(ROWS / 2) * FFH_;       // ff_w1^T pair [4096][512]
    u16* f1t_l = f1t_h + 4096 * 512;
    u16* f2t_h = f1t_l + 4096 * 512;                     // ff_w2^T pair [512][2048]
    u16* f2t_l = f2t_h + 512 * FFH_;
    float* fsin = (float*)((char*)big2 + (size_t)ROWS * 1536 * 4);
    float* fcos = fsin + F_ * 64;
    float* isin = fcos + F_ * 64;
    float* icos = isin + N_ * 64;
    u16* o_h = y_h;
    u16* o_l = y_l;

    rope_tables<<<2, 256, 0, stream>>>(fsin, fcos, isin, icos);

    // ---- patch embed ----
    convert_wt<<<dim3(DIM_ / 32, PATCH_K / 32), 256, 0, stream>>>(patch_w, wpt_h, wpt_l, PATCH_K, DIM_);
    rearrange_video_p<<<(ROWS * PATCH_K + 255) / 256, 256, 0, stream>>>(video, vp_h, vp_l);
    gemm_mfma3<0><<<dim3(DIM_ / 128, ROWS / 128), 256, 0, stream>>>(
        vp_h, vp_l, wpt_h, wpt_l, patch_b, x, ROWS, DIM_, PATCH_K);

    for (int l = 0; l < 4; ++l) {
        // convert this layer's attention weights
        convert_wt<<<dim3(1536 / 32, DIM_ / 32), 256, 0, stream>>>(
            qkv_t + (size_t)l * DIM_ * 1536, wqt_h, wqt_l, DIM_, 1536);
        convert_wt<<<dim3(DIM_ / 32, DIM_ / 32), 256, 0, stream>>>(
            out_t_w + (size_t)l * DIM_ * DIM_, wot_h, wot_l, DIM_, DIM_);
        convert_wt<<<dim3(1536 / 32, DIM_ / 32), 256, 0, stream>>>(
            qkv_s + (size_t)l * DIM_ * 1536, wqs_h, wqs_l, DIM_, 1536);
        convert_wt<<<dim3(DIM_ / 32, DIM_ / 32), 256, 0, stream>>>(
            out_s_w + (size_t)l * DIM_ * DIM_, wos_h, wos_l, DIM_, DIM_);

        // ---- time attention ----
        layernorm_p<<<ROWS, 64, 0, stream>>>(x, ln_t_g + l * DIM_, ln_t_b + l * DIM_, y_h, y_l);
        gemm_mfma3<0><<<dim3(1536 / 128, ROWS / 128), 256, 0, stream>>>(
            y_h, y_l, wqt_h, wqt_l, nullptr, qkv, ROWS, 1536, DIM_);
        attn_time<<<B_ * HEADS_ * N_, 64, 0, stream>>>(qkv, fsin, fcos, o_h, o_l);
        gemm_mfma3<1><<<dim3(DIM_ / 128, ROWS / 128), 256, 0, stream>>>(
            o_h, o_l, wot_h, wot_l, out_t_b + l * DIM_, x, ROWS, DIM_, DIM_);

        // ---- spatial attention ----
        layernorm_p<<<ROWS, 64, 0, stream>>>(x, ln_s_g + l * DIM_, ln_s_b + l * DIM_, y_h, y_l);
        gemm_mfma3<0><<<dim3(1536 / 128, ROWS / 128), 256, 0, stream>>>(
            y_h, y_l, wqs_h, wqs_l, nullptr, qkv, ROWS, 1536, DIM_);
        attn_space<<<B_ * HEADS_ * F_, 192, 0, stream>>>(qkv, isin, icos, o_h, o_l);
        gemm_mfma3<1><<<dim3(DIM_ / 128, ROWS / 128), 256, 0, stream>>>(
            o_h, o_l, wos_h, wos_l, out_s_b + l * DIM_, x, ROWS, DIM_, DIM_);

        // ---- FF with fused GLU (two M-halves; h2/ff-weights live in big2, qkv now dead) ----
        convert_wt<<<dim3(4096 / 32, DIM_ / 32), 256, 0, stream>>>(
            ff_w1 + (size_t)l * DIM_ * 2 * FFH_, f1t_h, f1t_l, DIM_, 4096);
        convert_wt<<<dim3(DIM_ / 32, FFH_ / 32), 256, 0, stream>>>(
            ff_w2 + (size_t)l * FFH_ * DIM_, f2t_h, f2t_l, FFH_, DIM_);
        layernorm_p<<<ROWS, 64, 0, stream>>>(x, ln_f_g + l * DIM_, ln_f_b + l * DIM_, y_h, y_l);
        const int MH = ROWS / 2;                 // 6144 rows per half
        for (int half = 0; half < 2; ++half) {
            const u16* yh = y_h + (size_t)half * MH * DIM_;
            const u16* yl = y_l + (size_t)half * MH * DIM_;
            float*     xh = x   + (size_t)half * MH * DIM_;
            gemm_glu3<<<dim3(FFH_ / 64, MH / 128), 256, 0, stream>>>(
                yh, yl, f1t_h, f1t_l, ff_b1 + l * 2 * FFH_, h2_h, h2_l);
            gemm_mfma3<1><<<dim3(DIM_ / 128, MH / 128), 256, 0, stream>>>(
                h2_h, h2_l, f2t_h, f2t_l, ff_b2 + l * DIM_, xh, MH, DIM_, FFH_);
        }
    }
}

// Round 5
// 3104.876 us; speedup vs baseline: 2.4961x; 1.2239x over previous
//
#include <hip/hip_runtime.h>
#include <math.h>

#define B_ 4
#define F_ 16
#define HP_ 12
#define WP_ 16
#define N_ 192            // HP*WP
#define S_ (F_*N_)        // 3072 tokens per batch
#define ROWS (B_*S_)      // 12288
#define DIM_ 512
#define HEADS_ 8
#define DH_ 64
#define FFH_ 2048
#define PATCH_K 192
#define PI_F 3.14159265358979323846f

typedef unsigned short u16;
typedef __attribute__((ext_vector_type(8))) short bf16x8;
typedef __attribute__((ext_vector_type(4))) float f32x4;

__device__ __forceinline__ u16 bf16_rne(float f) {
    unsigned int u = __float_as_uint(f);
    u += 0x7FFFu + ((u >> 16) & 1u);
    return (u16)(u >> 16);
}
__device__ __forceinline__ float bf16_f32(u16 h) {
    return __uint_as_float(((unsigned int)h) << 16);
}

// ---------------- RoPE tables ----------------
__global__ void rope_tables(float* __restrict__ fsin, float* __restrict__ fcos,
                            float* __restrict__ isin, float* __restrict__ icos) {
    int tid = blockIdx.x * blockDim.x + threadIdx.x;
    int stride = gridDim.x * blockDim.x;
    for (int idx = tid; idx < F_ * 64; idx += stride) {
        int f = idx >> 6, j = idx & 63;
        int i = j & 31;
        float inv = powf(10000.0f, -((float)i) / 32.0f);
        float fr = (float)f * inv;
        fsin[idx] = sinf(fr);
        fcos[idx] = cosf(fr);
    }
    for (int idx = tid; idx < N_ * 32; idx += stride) {
        int n = idx >> 5, k = idx & 31;
        int h = n / WP_, w = n % WP_;
        float scale = exp2f((float)(k & 15) * (log2f(5.0f) / 15.0f));
        float pos = (k < 16) ? (-1.0f + 2.0f * (float)h / (float)(HP_ - 1))
                             : (-1.0f + 2.0f * (float)w / (float)(WP_ - 1));
        float val = pos * scale * PI_F;
        float sv = sinf(val), cv = cosf(val);
        isin[n * 64 + 2 * k] = sv; isin[n * 64 + 2 * k + 1] = sv;
        icos[n * 64 + 2 * k] = cv; icos[n * 64 + 2 * k + 1] = cv;
    }
}

// ---------------- patch rearrange -> bf16 hi/lo planes ----------------
__global__ void rearrange_video_p(const float* __restrict__ video,
                                  u16* __restrict__ Vh, u16* __restrict__ Vl) {
    int t = blockIdx.x * blockDim.x + threadIdx.x;
    const int total = ROWS * PATCH_K;
    if (t >= total) return;
    int col = t % PATCH_K;
    int row = t / PATCH_K;
    int c  = col % 3;
    int pp = col / 3;
    int pi = pp >> 3, pj = pp & 7;
    int n  = row % N_;
    int bf = row / N_;
    int hp = n / WP_, wp = n % WP_;
    int hidx = hp * 8 + pi, widx = wp * 8 + pj;
    float f = video[((size_t)(bf * 3 + c) * 96 + hidx) * 128 + widx];
    u16 h = bf16_rne(f);
    Vh[t] = h;
    Vl[t] = bf16_rne(f - bf16_f32(h));
}

// ---------------- weight transpose + split: W[K][N] f32 -> Wt_hi/lo [N][K] bf16 ----------------
__global__ __launch_bounds__(256) void convert_wt(
    const float* __restrict__ W, u16* __restrict__ Wh, u16* __restrict__ Wl,
    int K, int N) {
    __shared__ float tile[32][33];
    int nb = blockIdx.x * 32, kb = blockIdx.y * 32;
    int tx = threadIdx.x & 31, ty = threadIdx.x >> 5;   // ty 0..7
    #pragma unroll
    for (int i = 0; i < 32; i += 8)
        tile[ty + i][tx] = W[(size_t)(kb + ty + i) * N + nb + tx];
    __syncthreads();
    #pragma unroll
    for (int i = 0; i < 32; i += 8) {
        int n = nb + ty + i, k = kb + tx;
        float f = tile[tx][ty + i];
        u16 h = bf16_rne(f);
        Wh[(size_t)n * K + k] = h;
        Wl[(size_t)n * K + k] = bf16_rne(f - bf16_f32(h));
    }
}

// ---------------- LayerNorm -> bf16 hi/lo planes ----------------
__global__ __launch_bounds__(64) void layernorm_p(
    const float* __restrict__ x, const float* __restrict__ g,
    const float* __restrict__ b, u16* __restrict__ Yh, u16* __restrict__ Yl) {
    int row = blockIdx.x;
    int lane = threadIdx.x;
    const float* xr = x + (size_t)row * DIM_;
    float4 v0 = *(const float4*)&xr[lane * 8];
    float4 v1 = *(const float4*)&xr[lane * 8 + 4];
    float s  = v0.x + v0.y + v0.z + v0.w + v1.x + v1.y + v1.z + v1.w;
    float sq = v0.x*v0.x + v0.y*v0.y + v0.z*v0.z + v0.w*v0.w
             + v1.x*v1.x + v1.y*v1.y + v1.z*v1.z + v1.w*v1.w;
    for (int off = 32; off; off >>= 1) { s += __shfl_xor(s, off); sq += __shfl_xor(sq, off); }
    float mu  = s * (1.0f / 512.0f);
    float var = sq * (1.0f / 512.0f) - mu * mu;
    float inv = rsqrtf(var + 1e-5f);
    float4 g0 = *(const float4*)&g[lane * 8];
    float4 g1 = *(const float4*)&g[lane * 8 + 4];
    float4 b0 = *(const float4*)&b[lane * 8];
    float4 b1 = *(const float4*)&b[lane * 8 + 4];
    float o[8];
    o[0] = (v0.x - mu) * inv * g0.x + b0.x;
    o[1] = (v0.y - mu) * inv * g0.y + b0.y;
    o[2] = (v0.z - mu) * inv * g0.z + b0.z;
    o[3] = (v0.w - mu) * inv * g0.w + b0.w;
    o[4] = (v1.x - mu) * inv * g1.x + b1.x;
    o[5] = (v1.y - mu) * inv * g1.y + b1.y;
    o[6] = (v1.z - mu) * inv * g1.z + b1.z;
    o[7] = (v1.w - mu) * inv * g1.w + b1.w;
    size_t ro = (size_t)row * DIM_ + lane * 8;
    ushort4 h0, h1, l0, l1;
    h0.x = bf16_rne(o[0]); l0.x = bf16_rne(o[0] - bf16_f32(h0.x));
    h0.y = bf16_rne(o[1]); l0.y = bf16_rne(o[1] - bf16_f32(h0.y));
    h0.z = bf16_rne(o[2]); l0.z = bf16_rne(o[2] - bf16_f32(h0.z));
    h0.w = bf16_rne(o[3]); l0.w = bf16_rne(o[3] - bf16_f32(h0.w));
    h1.x = bf16_rne(o[4]); l1.x = bf16_rne(o[4] - bf16_f32(h1.x));
    h1.y = bf16_rne(o[5]); l1.y = bf16_rne(o[5] - bf16_f32(h1.y));
    h1.z = bf16_rne(o[6]); l1.z = bf16_rne(o[6] - bf16_f32(h1.z));
    h1.w = bf16_rne(o[7]); l1.w = bf16_rne(o[7] - bf16_f32(h1.w));
    *(ushort4*)&Yh[ro]     = h0;
    *(ushort4*)&Yh[ro + 4] = h1;
    *(ushort4*)&Yl[ro]     = l0;
    *(ushort4*)&Yl[ro + 4] = l1;
}

// ---------------- split-bf16 MFMA GEMM: C = A@W^T(+bias)(+residual) ----------------
template<int EPI>   // 0: C = acc(+bias); 1: C += acc + bias
__global__ __launch_bounds__(256) void gemm_mfma3(
    const u16* __restrict__ Ah, const u16* __restrict__ Al,
    const u16* __restrict__ Wh, const u16* __restrict__ Wl,
    const float* __restrict__ bias, float* __restrict__ C,
    int M, int N, int K) {
    __shared__ u16 As[2][128 * 40];
    __shared__ u16 Ws[2][128 * 40];
    const int bm0 = blockIdx.y * 128, bn0 = blockIdx.x * 128;
    const int tid = threadIdx.x, lane = tid & 63, wid = tid >> 6;
    const int wm = (wid >> 1) * 64, wn = (wid & 1) * 64;
    const int fr = lane & 15, kg = (lane >> 4) * 8;
    f32x4 acc[4][4] = {};
    for (int k0 = 0; k0 < K; k0 += 32) {
        #pragma unroll
        for (int it = 0; it < 2; ++it) {
            int cc = it * 256 + tid;            // 0..511
            int row = cc >> 2, kc = (cc & 3) * 8;
            size_t ga = (size_t)(bm0 + row) * K + k0 + kc;
            size_t gw = (size_t)(bn0 + row) * K + k0 + kc;
            *(uint4*)&As[0][row * 40 + kc] = *(const uint4*)&Ah[ga];
            *(uint4*)&As[1][row * 40 + kc] = *(const uint4*)&Al[ga];
            *(uint4*)&Ws[0][row * 40 + kc] = *(const uint4*)&Wh[gw];
            *(uint4*)&Ws[1][row * 40 + kc] = *(const uint4*)&Wl[gw];
        }
        __syncthreads();
        bf16x8 ah[4], al[4], bh[4], bl[4];
        #pragma unroll
        for (int i = 0; i < 4; ++i) {
            ah[i] = *(const bf16x8*)&As[0][(wm + i * 16 + fr) * 40 + kg];
            al[i] = *(const bf16x8*)&As[1][(wm + i * 16 + fr) * 40 + kg];
            bh[i] = *(const bf16x8*)&Ws[0][(wn + i * 16 + fr) * 40 + kg];
            bl[i] = *(const bf16x8*)&Ws[1][(wn + i * 16 + fr) * 40 + kg];
        }
        #pragma unroll
        for (int i = 0; i < 4; ++i)
            #pragma unroll
            for (int j = 0; j < 4; ++j) {
                acc[i][j] = __builtin_amdgcn_mfma_f32_16x16x32_bf16(ah[i], bh[j], acc[i][j], 0, 0, 0);
                acc[i][j] = __builtin_amdgcn_mfma_f32_16x16x32_bf16(ah[i], bl[j], acc[i][j], 0, 0, 0);
                acc[i][j] = __builtin_amdgcn_mfma_f32_16x16x32_bf16(al[i], bh[j], acc[i][j], 0, 0, 0);
            }
        __syncthreads();
    }
    const int r0 = (lane >> 4) * 4;
    #pragma unroll
    for (int i = 0; i < 4; ++i)
        #pragma unroll
        for (int j = 0; j < 4; ++j) {
            int col = bn0 + wn + j * 16 + fr;
            float bb = bias ? bias[col] : 0.0f;
            #pragma unroll
            for (int r = 0; r < 4; ++r) {
                int row = bm0 + wm + i * 16 + r0 + r;
                float v = acc[i][j][r] + bb;
                size_t off = (size_t)row * N + col;
                if (EPI == 1) v += C[off];
                C[off] = v;
            }
        }
}

// ---------------- split-bf16 MFMA GEMM with fused GLU epilogue ----------------
__global__ __launch_bounds__(256) void gemm_glu3(
    const u16* __restrict__ Ah, const u16* __restrict__ Al,
    const u16* __restrict__ Wh, const u16* __restrict__ Wl,
    const float* __restrict__ bias, u16* __restrict__ Hh, u16* __restrict__ Hl) {
    const int K = DIM_;
    __shared__ u16 As[2][128 * 40];
    __shared__ u16 Ws[2][128 * 40];
    const int bm0 = blockIdx.y * 128, bn0 = blockIdx.x * 64;
    const int tid = threadIdx.x, lane = tid & 63, wid = tid >> 6;
    const int wm = (wid >> 1) * 64, wn2 = (wid & 1) * 32;
    const int fr = lane & 15, kg = (lane >> 4) * 8;
    f32x4 acca[4][2] = {}, accg[4][2] = {};
    for (int k0 = 0; k0 < K; k0 += 32) {
        #pragma unroll
        for (int it = 0; it < 2; ++it) {
            int cc = it * 256 + tid;
            int row = cc >> 2, kc = (cc & 3) * 8;
            size_t ga = (size_t)(bm0 + row) * K + k0 + kc;
            int ng = (row < 64) ? (bn0 + row) : (FFH_ + bn0 + row - 64);
            size_t gw = (size_t)ng * K + k0 + kc;
            *(uint4*)&As[0][row * 40 + kc] = *(const uint4*)&Ah[ga];
            *(uint4*)&As[1][row * 40 + kc] = *(const uint4*)&Al[ga];
            *(uint4*)&Ws[0][row * 40 + kc] = *(const uint4*)&Wh[gw];
            *(uint4*)&Ws[1][row * 40 + kc] = *(const uint4*)&Wl[gw];
        }
        __syncthreads();
        bf16x8 ah[4], al[4], bah[2], bal[2], bgh[2], bgl[2];
        #pragma unroll
        for (int i = 0; i < 4; ++i) {
            ah[i] = *(const bf16x8*)&As[0][(wm + i * 16 + fr) * 40 + kg];
            al[i] = *(const bf16x8*)&As[1][(wm + i * 16 + fr) * 40 + kg];
        }
        #pragma unroll
        for (int j = 0; j < 2; ++j) {
            bah[j] = *(const bf16x8*)&Ws[0][(wn2 + j * 16 + fr) * 40 + kg];
            bal[j] = *(const bf16x8*)&Ws[1][(wn2 + j * 16 + fr) * 40 + kg];
            bgh[j] = *(const bf16x8*)&Ws[0][(64 + wn2 + j * 16 + fr) * 40 + kg];
            bgl[j] = *(const bf16x8*)&Ws[1][(64 + wn2 + j * 16 + fr) * 40 + kg];
        }
        #pragma unroll
        for (int i = 0; i < 4; ++i)
            #pragma unroll
            for (int j = 0; j < 2; ++j) {
                acca[i][j] = __builtin_amdgcn_mfma_f32_16x16x32_bf16(ah[i], bah[j], acca[i][j], 0, 0, 0);
                acca[i][j] = __builtin_amdgcn_mfma_f32_16x16x32_bf16(ah[i], bal[j], acca[i][j], 0, 0, 0);
                acca[i][j] = __builtin_amdgcn_mfma_f32_16x16x32_bf16(al[i], bah[j], acca[i][j], 0, 0, 0);
                accg[i][j] = __builtin_amdgcn_mfma_f32_16x16x32_bf16(ah[i], bgh[j], accg[i][j], 0, 0, 0);
                accg[i][j] = __builtin_amdgcn_mfma_f32_16x16x32_bf16(ah[i], bgl[j], accg[i][j], 0, 0, 0);
                accg[i][j] = __builtin_amdgcn_mfma_f32_16x16x32_bf16(al[i], bgh[j], accg[i][j], 0, 0, 0);
            }
        __syncthreads();
    }
    const int r0 = (lane >> 4) * 4;
    #pragma unroll
    for (int i = 0; i < 4; ++i)
        #pragma unroll
        for (int j = 0; j < 2; ++j) {
            int col = bn0 + wn2 + j * 16 + fr;
            float ba = bias[col], bg = bias[FFH_ + col];
            #pragma unroll
            for (int r = 0; r < 4; ++r) {
                int row = bm0 + wm + i * 16 + r0 + r;
                float av = acca[i][j][r] + ba;
                float gv = accg[i][j][r] + bg;
                float gl = 0.5f * gv * (1.0f + erff(gv * 0.70710678118654752f));
                float v = av * gl;
                u16 h = bf16_rne(v);
                size_t off = (size_t)row * FFH_ + col;
                Hh[off] = h;
                Hl[off] = bf16_rne(v - bf16_f32(h));
            }
        }
}

// ---------------- time attention: one wave per (b,h,n) ----------------
__global__ __launch_bounds__(64) void attn_time(
    const float* __restrict__ qkv, const float* __restrict__ fsin,
    const float* __restrict__ fcos, u16* __restrict__ Oh, u16* __restrict__ Ol) {
    int bid = blockIdx.x;               // b*HEADS_*N_ + h*N_ + n
    int n = bid % N_;
    int h = (bid / N_) % HEADS_;
    int b = bid / (N_ * HEADS_);
    int lane = threadIdx.x;             // = d
    __shared__ float qs[16][68], ks[16][68], vs[16][68], Pm[16][16];
    int parity = lane & 1;
    for (int f = 0; f < F_; ++f) {
        size_t base = (size_t)(b * S_ + f * N_ + n) * 1536 + h * 64;
        float qv = qkv[base + lane] * 0.125f;
        float kv = qkv[base + 512 + lane];
        float vv = qkv[base + 1024 + lane];
        float sn = fsin[f * 64 + lane], cs = fcos[f * 64 + lane];
        float qx = __shfl_xor(qv, 1);
        float kx = __shfl_xor(kv, 1);
        float qrot = parity ? qx : -qx;
        float krot = parity ? kx : -kx;
        qs[f][lane] = qv * cs + qrot * sn;
        ks[f][lane] = kv * cs + krot * sn;
        vs[f][lane] = vv;
    }
    __syncthreads();
    int j = lane & 15, r = lane >> 4;
    for (int rr = 0; rr < 4; ++rr) {
        int i = rr * 4 + r;
        float sacc = 0.f;
        #pragma unroll
        for (int d4 = 0; d4 < 16; ++d4) {
            float4 qa = *(const float4*)&qs[i][d4 * 4];
            float4 ka = *(const float4*)&ks[j][d4 * 4];
            sacc += qa.x*ka.x + qa.y*ka.y + qa.z*ka.z + qa.w*ka.w;
        }
        float mx = sacc;
        for (int off = 8; off; off >>= 1) mx = fmaxf(mx, __shfl_xor(mx, off));
        float p = expf(sacc - mx);
        float sum = p;
        for (int off = 8; off; off >>= 1) sum += __shfl_xor(sum, off);
        Pm[i][j] = p / sum;
    }
    __syncthreads();
    for (int i = 0; i < 16; ++i) {
        float acc = 0.f;
        #pragma unroll
        for (int jj = 0; jj < 16; ++jj) acc += Pm[i][jj] * vs[jj][lane];
        size_t ob = (size_t)(b * S_ + i * N_ + n) * 512 + h * 64 + lane;
        u16 hh = bf16_rne(acc);
        Oh[ob] = hh;
        Ol[ob] = bf16_rne(acc - bf16_f32(hh));
    }
}

// ---------------- spatial attention, MFMA flash version ----------------
// Block = (b,h,f): 4 waves x 48 q-rows. Q in registers (A-frags, RoPE+scale+split).
// KV tiles of 32 keys: K staged [key][d] (B-frags for QK^T), V staged transposed
// [d][key] (B-frags for PV). Split-3 MFMA both matmuls; online softmax in regs;
// P -> per-wave LDS pair -> A-frags. C/D layout: col=lane&15, row=(lane>>4)*4+reg.
__global__ __launch_bounds__(256, 2) void attn_space_mfma(
    const float* __restrict__ qkv, const float* __restrict__ isin,
    const float* __restrict__ icos, u16* __restrict__ Oh, u16* __restrict__ Ol) {
    int bid = blockIdx.x;               // b*HEADS_*F_ + h*F_ + f
    int f = bid % F_;
    int h = (bid / F_) % HEADS_;
    int b = bid / (F_ * HEADS_);
    const int tid = threadIdx.x, lane = tid & 63, wid = tid >> 6;
    const int fr = lane & 15, g = lane >> 4;        // kg = g*8
    __shared__ u16 Ksh[32][72], Ksl[32][72];        // [key][d]
    __shared__ u16 Vsh[64][40], Vsl[64][40];        // transposed [d][key]
    __shared__ u16 Psh[4][48][40], Psl[4][48][40];  // per-wave P pair
    const size_t rowbase = (size_t)b * S_ + (size_t)f * N_;

    // ---- load Q as A-fragments: rows wid*48 + i*16 + fr, k = ks*32 + g*8 + e ----
    bf16x8 qh[3][2], ql[3][2];
    #pragma unroll
    for (int i = 0; i < 3; ++i) {
        int n = wid * 48 + i * 16 + fr;
        #pragma unroll
        for (int ks = 0; ks < 2; ++ks) {
            int dbase = ks * 32 + g * 8;
            const float* qp = &qkv[(rowbase + n) * 1536 + h * 64 + dbase];
            float4 t0 = *(const float4*)qp;
            float4 t1 = *(const float4*)(qp + 4);
            float4 s0 = *(const float4*)&isin[n * 64 + dbase];
            float4 s1 = *(const float4*)&isin[n * 64 + dbase + 4];
            float4 c0 = *(const float4*)&icos[n * 64 + dbase];
            float4 c1 = *(const float4*)&icos[n * 64 + dbase + 4];
            float v[8];
            v[0] = (t0.x * c0.x - t0.y * s0.x) * 0.125f;
            v[1] = (t0.y * c0.y + t0.x * s0.y) * 0.125f;
            v[2] = (t0.z * c0.z - t0.w * s0.z) * 0.125f;
            v[3] = (t0.w * c0.w + t0.z * s0.w) * 0.125f;
            v[4] = (t1.x * c1.x - t1.y * s1.x) * 0.125f;
            v[5] = (t1.y * c1.y + t1.x * s1.y) * 0.125f;
            v[6] = (t1.z * c1.z - t1.w * s1.z) * 0.125f;
            v[7] = (t1.w * c1.w + t1.z * s1.w) * 0.125f;
            bf16x8 hh, ll;
            #pragma unroll
            for (int e = 0; e < 8; ++e) {
                u16 hb = bf16_rne(v[e]);
                hh[e] = (short)hb;
                ll[e] = (short)bf16_rne(v[e] - bf16_f32(hb));
            }
            qh[i][ks] = hh; ql[i][ks] = ll;
        }
    }

    float m[3][4], l[3][4];
    f32x4 oacc[3][4] = {};
    #pragma unroll
    for (int i = 0; i < 3; ++i)
        #pragma unroll
        for (int r = 0; r < 4; ++r) { m[i][r] = -3.0e38f; l[i][r] = 0.0f; }

    for (int kt = 0; kt < 6; ++kt) {            // keys kt*32 .. +32
        __syncthreads();                         // guard prior-tile frag reads
        // ---- stage K tile with RoPE: 32 rows x 16 float4-chunks = 512 items ----
        #pragma unroll
        for (int it = 0; it < 2; ++it) {
            int c = it * 256 + tid;
            int kr = c >> 4, dseg = (c & 15) * 4;
            int nk = kt * 32 + kr;
            float4 t = *(const float4*)&qkv[(rowbase + nk) * 1536 + 512 + h * 64 + dseg];
            float4 sn = *(const float4*)&isin[nk * 64 + dseg];
            float4 cs = *(const float4*)&icos[nk * 64 + dseg];
            float v0 = t.x * cs.x - t.y * sn.x;
            float v1 = t.y * cs.y + t.x * sn.y;
            float v2 = t.z * cs.z - t.w * sn.z;
            float v3 = t.w * cs.w + t.z * sn.w;
            ushort4 hh, ll;
            hh.x = bf16_rne(v0); ll.x = bf16_rne(v0 - bf16_f32(hh.x));
            hh.y = bf16_rne(v1); ll.y = bf16_rne(v1 - bf16_f32(hh.y));
            hh.z = bf16_rne(v2); ll.z = bf16_rne(v2 - bf16_f32(hh.z));
            hh.w = bf16_rne(v3); ll.w = bf16_rne(v3 - bf16_f32(hh.w));
            *(ushort4*)&Ksh[kr][dseg] = hh;
            *(ushort4*)&Ksl[kr][dseg] = ll;
        }
        // ---- stage V transposed: thread (kr = tid&31, ds8 = tid>>5) ----
        {
            int kr = tid & 31, ds8 = tid >> 5;
            const float* vp = &qkv[(rowbase + kt * 32 + kr) * 1536 + 1024 + h * 64 + ds8 * 8];
            float4 a = *(const float4*)vp;
            float4 b4 = *(const float4*)(vp + 4);
            float vv[8] = {a.x, a.y, a.z, a.w, b4.x, b4.y, b4.z, b4.w};
            #pragma unroll
            for (int e = 0; e < 8; ++e) {
                u16 hb = bf16_rne(vv[e]);
                Vsh[ds8 * 8 + e][kr] = hb;
                Vsl[ds8 * 8 + e][kr] = bf16_rne(vv[e] - bf16_f32(hb));
            }
        }
        __syncthreads();
        // ---- S = Q K^T for this tile (2 col-frags x 2 k-steps, split-3) ----
        bf16x8 kbh[2][2], kbl[2][2];
        #pragma unroll
        for (int j = 0; j < 2; ++j)
            #pragma unroll
            for (int ks = 0; ks < 2; ++ks) {
                kbh[j][ks] = *(const bf16x8*)&Ksh[j * 16 + fr][ks * 32 + g * 8];
                kbl[j][ks] = *(const bf16x8*)&Ksl[j * 16 + fr][ks * 32 + g * 8];
            }
        f32x4 s[3][2] = {};
        #pragma unroll
        for (int i = 0; i < 3; ++i)
            #pragma unroll
            for (int j = 0; j < 2; ++j)
                #pragma unroll
                for (int ks = 0; ks < 2; ++ks) {
                    s[i][j] = __builtin_amdgcn_mfma_f32_16x16x32_bf16(qh[i][ks], kbh[j][ks], s[i][j], 0, 0, 0);
                    s[i][j] = __builtin_amdgcn_mfma_f32_16x16x32_bf16(qh[i][ks], kbl[j][ks], s[i][j], 0, 0, 0);
                    s[i][j] = __builtin_amdgcn_mfma_f32_16x16x32_bf16(ql[i][ks], kbh[j][ks], s[i][j], 0, 0, 0);
                }
        // ---- online softmax + P -> LDS ----
        #pragma unroll
        for (int i = 0; i < 3; ++i) {
            float tmax[4], mn[4], corr[4], psum[4];
            #pragma unroll
            for (int r = 0; r < 4; ++r) tmax[r] = fmaxf(s[i][0][r], s[i][1][r]);
            #pragma unroll
            for (int off = 8; off; off >>= 1)
                #pragma unroll
                for (int r = 0; r < 4; ++r) tmax[r] = fmaxf(tmax[r], __shfl_xor(tmax[r], off));
            float p0[4], p1[4];
            #pragma unroll
            for (int r = 0; r < 4; ++r) {
                mn[r] = fmaxf(m[i][r], tmax[r]);
                corr[r] = expf(m[i][r] - mn[r]);
                p0[r] = expf(s[i][0][r] - mn[r]);
                p1[r] = expf(s[i][1][r] - mn[r]);
                psum[r] = p0[r] + p1[r];
                m[i][r] = mn[r];
            }
            #pragma unroll
            for (int off = 8; off; off >>= 1)
                #pragma unroll
                for (int r = 0; r < 4; ++r) psum[r] += __shfl_xor(psum[r], off);
            #pragma unroll
            for (int r = 0; r < 4; ++r) l[i][r] = l[i][r] * corr[r] + psum[r];
            #pragma unroll
            for (int dj = 0; dj < 4; ++dj)
                #pragma unroll
                for (int r = 0; r < 4; ++r) oacc[i][dj][r] *= corr[r];
            // P element (row_local = i*16 + g*4 + r, key_local = j*16 + fr)
            #pragma unroll
            for (int r = 0; r < 4; ++r) {
                int rl = i * 16 + g * 4 + r;
                u16 h0 = bf16_rne(p0[r]);
                Psh[wid][rl][fr]      = h0;
                Psl[wid][rl][fr]      = bf16_rne(p0[r] - bf16_f32(h0));
                u16 h1 = bf16_rne(p1[r]);
                Psh[wid][rl][16 + fr] = h1;
                Psl[wid][rl][16 + fr] = bf16_rne(p1[r] - bf16_f32(h1));
            }
        }
        // ---- O += P V (1 k-step over 32 keys, split-3); P wave-local (no barrier) ----
        bf16x8 pah[3], pal[3];
        #pragma unroll
        for (int i = 0; i < 3; ++i) {
            pah[i] = *(const bf16x8*)&Psh[wid][i * 16 + fr][g * 8];
            pal[i] = *(const bf16x8*)&Psl[wid][i * 16 + fr][g * 8];
        }
        bf16x8 vbh[4], vbl[4];
        #pragma unroll
        for (int dj = 0; dj < 4; ++dj) {
            vbh[dj] = *(const bf16x8*)&Vsh[dj * 16 + fr][g * 8];
            vbl[dj] = *(const bf16x8*)&Vsl[dj * 16 + fr][g * 8];
        }
        #pragma unroll
        for (int i = 0; i < 3; ++i)
            #pragma unroll
            for (int dj = 0; dj < 4; ++dj) {
                oacc[i][dj] = __builtin_amdgcn_mfma_f32_16x16x32_bf16(pah[i], vbh[dj], oacc[i][dj], 0, 0, 0);
                oacc[i][dj] = __builtin_amdgcn_mfma_f32_16x16x32_bf16(pah[i], vbl[dj], oacc[i][dj], 0, 0, 0);
                oacc[i][dj] = __builtin_amdgcn_mfma_f32_16x16x32_bf16(pal[i], vbh[dj], oacc[i][dj], 0, 0, 0);
            }
    }
    // ---- epilogue: O / l -> bf16 pair ----
    #pragma unroll
    for (int i = 0; i < 3; ++i) {
        #pragma unroll
        for (int r = 0; r < 4; ++r) {
            int row = wid * 48 + i * 16 + g * 4 + r;
            float invl = 1.0f / l[i][r];
            #pragma unroll
            for (int dj = 0; dj < 4; ++dj) {
                float v = oacc[i][dj][r] * invl;
                size_t ob = (rowbase + row) * 512 + h * 64 + dj * 16 + fr;
                u16 hh = bf16_rne(v);
                Oh[ob] = hh;
                Ol[ob] = bf16_rne(v - bf16_f32(hh));
            }
        }
    }
}

extern "C" void kernel_launch(void* const* d_in, const int* in_sizes, int n_in,
                              void* d_out, int out_size, void* d_ws, size_t ws_size,
                              hipStream_t stream) {
    (void)in_sizes; (void)n_in; (void)out_size; (void)ws_size;
    const float* video   = (const float*)d_in[0];
    const float* patch_w = (const float*)d_in[1];
    const float* patch_b = (const float*)d_in[2];
    const float* ln_t_g  = (const float*)d_in[3];
    const float* ln_t_b  = (const float*)d_in[4];
    const float* ln_s_g  = (const float*)d_in[5];
    const float* ln_s_b  = (const float*)d_in[6];
    const float* ln_f_g  = (const float*)d_in[7];
    const float* ln_f_b  = (const float*)d_in[8];
    const float* qkv_t   = (const float*)d_in[9];
    const float* out_t_w = (const float*)d_in[10];
    const float* out_t_b = (const float*)d_in[11];
    const float* qkv_s   = (const float*)d_in[12];
    const float* out_s_w = (const float*)d_in[13];
    const float* out_s_b = (const float*)d_in[14];
    const float* ff_w1   = (const float*)d_in[15];
    const float* ff_b1   = (const float*)d_in[16];
    const float* ff_w2   = (const float*)d_in[17];
    const float* ff_b2   = (const float*)d_in[18];

    float* x = (float*)d_out;                   // [12288][512] residual stream

    // ---- workspace layout (~104.5 MB) ----
    u16* wqt_h = (u16*)d_ws;                    // qkv_t^T pair [1536][512]
    u16* wqt_l = wqt_h + 1536 * 512;
    u16* wot_h = wqt_l + 1536 * 512;            // out_t^T pair [512][512]
    u16* wot_l = wot_h + 512 * 512;
    u16* wqs_h = wot_l + 512 * 512;
    u16* wqs_l = wqs_h + 1536 * 512;
    u16* wos_h = wqs_l + 1536 * 512;
    u16* wos_l = wos_h + 512 * 512;
    u16* wpt_h = wos_l + 512 * 512;             // patch_w^T pair [512][192]
    u16* wpt_l = wpt_h + 512 * PATCH_K;
    u16* y_h   = wpt_l + 512 * PATCH_K;         // activation pair [12288][512]; o aliases y
    u16* y_l   = y_h + (size_t)ROWS * DIM_;
    float* big2 = (float*)(y_l + (size_t)ROWS * DIM_);  // 75.5 MB multi-use region
    float* qkv  = big2;                                  // [12288][1536] fp32
    u16* vp_h = (u16*)big2;                              // patch pre pair [12288][192]
    u16* vp_l = vp_h + (size_t)ROWS * PATCH_K;
    u16* h2_h = (u16*)big2;                              // FF phase: [6144][2048] pair
    u16* h2_l = h2_h + (size_t)(ROWS / 2) * FFH_;
    u16* f1t_h = h2_l + (size_t)(ROWS / 2) * FFH_;       // ff_w1^T pair [4096][512]
    u16* f1t_l = f1t_h + 4096 * 512;
    u16* f2t_h = f1t_l + 4096 * 512;                     // ff_w2^T pair [512][2048]
    u16* f2t_l = f2t_h + 512 * FFH_;
    float* fsin = (float*)((char*)big2 + (size_t)ROWS * 1536 * 4);
    float* fcos = fsin + F_ * 64;
    float* isin = fcos + F_ * 64;
    float* icos = isin + N_ * 64;
    u16* o_h = y_h;
    u16* o_l = y_l;

    rope_tables<<<2, 256, 0, stream>>>(fsin, fcos, isin, icos);

    // ---- patch embed ----
    convert_wt<<<dim3(DIM_ / 32, PATCH_K / 32), 256, 0, stream>>>(patch_w, wpt_h, wpt_l, PATCH_K, DIM_);
    rearrange_video_p<<<(ROWS * PATCH_K + 255) / 256, 256, 0, stream>>>(video, vp_h, vp_l);
    gemm_mfma3<0><<<dim3(DIM_ / 128, ROWS / 128), 256, 0, stream>>>(
        vp_h, vp_l, wpt_h, wpt_l, patch_b, x, ROWS, DIM_, PATCH_K);

    for (int l = 0; l < 4; ++l) {
        // convert this layer's attention weights
        convert_wt<<<dim3(1536 / 32, DIM_ / 32), 256, 0, stream>>>(
            qkv_t + (size_t)l * DIM_ * 1536, wqt_h, wqt_l, DIM_, 1536);
        convert_wt<<<dim3(DIM_ / 32, DIM_ / 32), 256, 0, stream>>>(
            out_t_w + (size_t)l * DIM_ * DIM_, wot_h, wot_l, DIM_, DIM_);
        convert_wt<<<dim3(1536 / 32, DIM_ / 32), 256, 0, stream>>>(
            qkv_s + (size_t)l * DIM_ * 1536, wqs_h, wqs_l, DIM_, 1536);
        convert_wt<<<dim3(DIM_ / 32, DIM_ / 32), 256, 0, stream>>>(
            out_s_w + (size_t)l * DIM_ * DIM_, wos_h, wos_l, DIM_, DIM_);

        // ---- time attention ----
        layernorm_p<<<ROWS, 64, 0, stream>>>(x, ln_t_g + l * DIM_, ln_t_b + l * DIM_, y_h, y_l);
        gemm_mfma3<0><<<dim3(1536 / 128, ROWS / 128), 256, 0, stream>>>(
            y_h, y_l, wqt_h, wqt_l, nullptr, qkv, ROWS, 1536, DIM_);
        attn_time<<<B_ * HEADS_ * N_, 64, 0, stream>>>(qkv, fsin, fcos, o_h, o_l);
        gemm_mfma3<1><<<dim3(DIM_ / 128, ROWS / 128), 256, 0, stream>>>(
            o_h, o_l, wot_h, wot_l, out_t_b + l * DIM_, x, ROWS, DIM_, DIM_);

        // ---- spatial attention (MFMA flash) ----
        layernorm_p<<<ROWS, 64, 0, stream>>>(x, ln_s_g + l * DIM_, ln_s_b + l * DIM_, y_h, y_l);
        gemm_mfma3<0><<<dim3(1536 / 128, ROWS / 128), 256, 0, stream>>>(
            y_h, y_l, wqs_h, wqs_l, nullptr, qkv, ROWS, 1536, DIM_);
        attn_space_mfma<<<B_ * HEADS_ * F_, 256, 0, stream>>>(qkv, isin, icos, o_h, o_l);
        gemm_mfma3<1><<<dim3(DIM_ / 128, ROWS / 128), 256, 0, stream>>>(
            o_h, o_l, wos_h, wos_l, out_s_b + l * DIM_, x, ROWS, DIM_, DIM_);

        // ---- FF with fused GLU (two M-halves) ----
        convert_wt<<<dim3(4096 / 32, DIM_ / 32), 256, 0, stream>>>(
            ff_w1 + (size_t)l * DIM_ * 2 * FFH_, f1t_h, f1t_l, DIM_, 4096);
        convert_wt<<<dim3(DIM_ / 32, FFH_ / 32), 256, 0, stream>>>(
            ff_w2 + (size_t)l * FFH_ * DIM_, f2t_h, f2t_l, FFH_, DIM_);
        layernorm_p<<<ROWS, 64, 0, stream>>>(x, ln_f_g + l * DIM_, ln_f_b + l * DIM_, y_h, y_l);
        const int MH = ROWS / 2;                 // 6144 rows per half
        for (int half = 0; half < 2; ++half) {
            const u16* yh = y_h + (size_t)half * MH * DIM_;
            const u16* yl = y_l + (size_t)half * MH * DIM_;
            float*     xh = x   + (size_t)half * MH * DIM_;
            gemm_glu3<<<dim3(FFH_ / 64, MH / 128), 256, 0, stream>>>(
                yh, yl, f1t_h, f1t_l, ff_b1 + l * 2 * FFH_, h2_h, h2_l);
            gemm_mfma3<1><<<dim3(DIM_ / 128, MH / 128), 256, 0, stream>>>(
                h2_h, h2_l, f2t_h, f2t_l, ff_b2 + l * DIM_, xh, MH, DIM_, FFH_);
        }
    }
}

// Round 6
// 2542.315 us; speedup vs baseline: 3.0484x; 1.2213x over previous
//
#include <hip/hip_runtime.h>
#include <math.h>

#define B_ 4
#define F_ 16
#define HP_ 12
#define WP_ 16
#define N_ 192            // HP*WP
#define S_ (F_*N_)        // 3072 tokens per batch
#define ROWS (B_*S_)      // 12288
#define DIM_ 512
#define HEADS_ 8
#define DH_ 64
#define FFH_ 2048
#define PATCH_K 192
#define PI_F 3.14159265358979323846f

typedef unsigned short u16;
typedef __attribute__((ext_vector_type(8))) short bf16x8;
typedef __attribute__((ext_vector_type(4))) float f32x4;

__device__ __forceinline__ u16 bf16_rne(float f) {
    unsigned int u = __float_as_uint(f);
    u += 0x7FFFu + ((u >> 16) & 1u);
    return (u16)(u >> 16);
}
__device__ __forceinline__ float bf16_f32(u16 h) {
    return __uint_as_float(((unsigned int)h) << 16);
}

// XCD-aware chunked block swizzle (T1): keep M-panels resident per-XCD L2.
// Requires gridDim.x*gridDim.y % 8 == 0 (all our grids satisfy this).
__device__ __forceinline__ void swz2d(int& bx, int& by) {
    int gx = gridDim.x;
    int nwg = gx * gridDim.y;
    int id = by * gx + bx;
    if ((nwg & 7) == 0) {
        int cpx = nwg >> 3;
        int wg = (id & 7) * cpx + (id >> 3);
        bx = wg % gx;
        by = wg / gx;
    }
}

// ---------------- RoPE tables ----------------
__global__ void rope_tables(float* __restrict__ fsin, float* __restrict__ fcos,
                            float* __restrict__ isin, float* __restrict__ icos) {
    int tid = blockIdx.x * blockDim.x + threadIdx.x;
    int stride = gridDim.x * blockDim.x;
    for (int idx = tid; idx < F_ * 64; idx += stride) {
        int f = idx >> 6, j = idx & 63;
        int i = j & 31;
        float inv = powf(10000.0f, -((float)i) / 32.0f);
        float fr = (float)f * inv;
        fsin[idx] = sinf(fr);
        fcos[idx] = cosf(fr);
    }
    for (int idx = tid; idx < N_ * 32; idx += stride) {
        int n = idx >> 5, k = idx & 31;
        int h = n / WP_, w = n % WP_;
        float scale = exp2f((float)(k & 15) * (log2f(5.0f) / 15.0f));
        float pos = (k < 16) ? (-1.0f + 2.0f * (float)h / (float)(HP_ - 1))
                             : (-1.0f + 2.0f * (float)w / (float)(WP_ - 1));
        float val = pos * scale * PI_F;
        float sv = sinf(val), cv = cosf(val);
        isin[n * 64 + 2 * k] = sv; isin[n * 64 + 2 * k + 1] = sv;
        icos[n * 64 + 2 * k] = cv; icos[n * 64 + 2 * k + 1] = cv;
    }
}

// ---------------- patch rearrange -> bf16 hi/lo planes ----------------
__global__ void rearrange_video_p(const float* __restrict__ video,
                                  u16* __restrict__ Vh, u16* __restrict__ Vl) {
    int t = blockIdx.x * blockDim.x + threadIdx.x;
    const int total = ROWS * PATCH_K;
    if (t >= total) return;
    int col = t % PATCH_K;
    int row = t / PATCH_K;
    int c  = col % 3;
    int pp = col / 3;
    int pi = pp >> 3, pj = pp & 7;
    int n  = row % N_;
    int bf = row / N_;
    int hp = n / WP_, wp = n % WP_;
    int hidx = hp * 8 + pi, widx = wp * 8 + pj;
    float f = video[((size_t)(bf * 3 + c) * 96 + hidx) * 128 + widx];
    u16 h = bf16_rne(f);
    Vh[t] = h;
    Vl[t] = bf16_rne(f - bf16_f32(h));
}

// ---------------- weight transpose + split: W[K][N] f32 -> Wt_hi/lo [N][K] bf16 ----------------
__global__ __launch_bounds__(256) void convert_wt(
    const float* __restrict__ W, u16* __restrict__ Wh, u16* __restrict__ Wl,
    int K, int N) {
    __shared__ float tile[32][33];
    int nb = blockIdx.x * 32, kb = blockIdx.y * 32;
    int tx = threadIdx.x & 31, ty = threadIdx.x >> 5;   // ty 0..7
    #pragma unroll
    for (int i = 0; i < 32; i += 8)
        tile[ty + i][tx] = W[(size_t)(kb + ty + i) * N + nb + tx];
    __syncthreads();
    #pragma unroll
    for (int i = 0; i < 32; i += 8) {
        int n = nb + ty + i, k = kb + tx;
        float f = tile[tx][ty + i];
        u16 h = bf16_rne(f);
        Wh[(size_t)n * K + k] = h;
        Wl[(size_t)n * K + k] = bf16_rne(f - bf16_f32(h));
    }
}

// ---------------- LayerNorm -> bf16 hi/lo planes ----------------
__global__ __launch_bounds__(64) void layernorm_p(
    const float* __restrict__ x, const float* __restrict__ g,
    const float* __restrict__ b, u16* __restrict__ Yh, u16* __restrict__ Yl) {
    int row = blockIdx.x;
    int lane = threadIdx.x;
    const float* xr = x + (size_t)row * DIM_;
    float4 v0 = *(const float4*)&xr[lane * 8];
    float4 v1 = *(const float4*)&xr[lane * 8 + 4];
    float s  = v0.x + v0.y + v0.z + v0.w + v1.x + v1.y + v1.z + v1.w;
    float sq = v0.x*v0.x + v0.y*v0.y + v0.z*v0.z + v0.w*v0.w
             + v1.x*v1.x + v1.y*v1.y + v1.z*v1.z + v1.w*v1.w;
    for (int off = 32; off; off >>= 1) { s += __shfl_xor(s, off); sq += __shfl_xor(sq, off); }
    float mu  = s * (1.0f / 512.0f);
    float var = sq * (1.0f / 512.0f) - mu * mu;
    float inv = rsqrtf(var + 1e-5f);
    float4 g0 = *(const float4*)&g[lane * 8];
    float4 g1 = *(const float4*)&g[lane * 8 + 4];
    float4 b0 = *(const float4*)&b[lane * 8];
    float4 b1 = *(const float4*)&b[lane * 8 + 4];
    float o[8];
    o[0] = (v0.x - mu) * inv * g0.x + b0.x;
    o[1] = (v0.y - mu) * inv * g0.y + b0.y;
    o[2] = (v0.z - mu) * inv * g0.z + b0.z;
    o[3] = (v0.w - mu) * inv * g0.w + b0.w;
    o[4] = (v1.x - mu) * inv * g1.x + b1.x;
    o[5] = (v1.y - mu) * inv * g1.y + b1.y;
    o[6] = (v1.z - mu) * inv * g1.z + b1.z;
    o[7] = (v1.w - mu) * inv * g1.w + b1.w;
    size_t ro = (size_t)row * DIM_ + lane * 8;
    ushort4 h0, h1, l0, l1;
    h0.x = bf16_rne(o[0]); l0.x = bf16_rne(o[0] - bf16_f32(h0.x));
    h0.y = bf16_rne(o[1]); l0.y = bf16_rne(o[1] - bf16_f32(h0.y));
    h0.z = bf16_rne(o[2]); l0.z = bf16_rne(o[2] - bf16_f32(h0.z));
    h0.w = bf16_rne(o[3]); l0.w = bf16_rne(o[3] - bf16_f32(h0.w));
    h1.x = bf16_rne(o[4]); l1.x = bf16_rne(o[4] - bf16_f32(h1.x));
    h1.y = bf16_rne(o[5]); l1.y = bf16_rne(o[5] - bf16_f32(h1.y));
    h1.z = bf16_rne(o[6]); l1.z = bf16_rne(o[6] - bf16_f32(h1.z));
    h1.w = bf16_rne(o[7]); l1.w = bf16_rne(o[7] - bf16_f32(h1.w));
    *(ushort4*)&Yh[ro]     = h0;
    *(ushort4*)&Yh[ro + 4] = h1;
    *(ushort4*)&Yl[ro]     = l0;
    *(ushort4*)&Yl[ro + 4] = l1;
}

// ---------------- split-bf16 MFMA GEMM, 128x128 tile (used for qkv, N=1536) ----------------
template<int EPI>
__global__ __launch_bounds__(256) void gemm_mfma3(
    const u16* __restrict__ Ah, const u16* __restrict__ Al,
    const u16* __restrict__ Wh, const u16* __restrict__ Wl,
    const float* __restrict__ bias, float* __restrict__ C,
    int M, int N, int K) {
    __shared__ u16 As[2][128 * 40];
    __shared__ u16 Ws[2][128 * 40];
    int bx = blockIdx.x, by = blockIdx.y;
    swz2d(bx, by);
    const int bm0 = by * 128, bn0 = bx * 128;
    const int tid = threadIdx.x, lane = tid & 63, wid = tid >> 6;
    const int wm = (wid >> 1) * 64, wn = (wid & 1) * 64;
    const int fr = lane & 15, kg = (lane >> 4) * 8;
    f32x4 acc[4][4] = {};
    for (int k0 = 0; k0 < K; k0 += 32) {
        #pragma unroll
        for (int it = 0; it < 2; ++it) {
            int cc = it * 256 + tid;            // 0..511
            int row = cc >> 2, kc = (cc & 3) * 8;
            size_t ga = (size_t)(bm0 + row) * K + k0 + kc;
            size_t gw = (size_t)(bn0 + row) * K + k0 + kc;
            *(uint4*)&As[0][row * 40 + kc] = *(const uint4*)&Ah[ga];
            *(uint4*)&As[1][row * 40 + kc] = *(const uint4*)&Al[ga];
            *(uint4*)&Ws[0][row * 40 + kc] = *(const uint4*)&Wh[gw];
            *(uint4*)&Ws[1][row * 40 + kc] = *(const uint4*)&Wl[gw];
        }
        __syncthreads();
        bf16x8 ah[4], al[4], bh[4], bl[4];
        #pragma unroll
        for (int i = 0; i < 4; ++i) {
            ah[i] = *(const bf16x8*)&As[0][(wm + i * 16 + fr) * 40 + kg];
            al[i] = *(const bf16x8*)&As[1][(wm + i * 16 + fr) * 40 + kg];
            bh[i] = *(const bf16x8*)&Ws[0][(wn + i * 16 + fr) * 40 + kg];
            bl[i] = *(const bf16x8*)&Ws[1][(wn + i * 16 + fr) * 40 + kg];
        }
        #pragma unroll
        for (int i = 0; i < 4; ++i)
            #pragma unroll
            for (int j = 0; j < 4; ++j) {
                acc[i][j] = __builtin_amdgcn_mfma_f32_16x16x32_bf16(ah[i], bh[j], acc[i][j], 0, 0, 0);
                acc[i][j] = __builtin_amdgcn_mfma_f32_16x16x32_bf16(ah[i], bl[j], acc[i][j], 0, 0, 0);
                acc[i][j] = __builtin_amdgcn_mfma_f32_16x16x32_bf16(al[i], bh[j], acc[i][j], 0, 0, 0);
            }
        __syncthreads();
    }
    const int r0 = (lane >> 4) * 4;
    #pragma unroll
    for (int i = 0; i < 4; ++i)
        #pragma unroll
        for (int j = 0; j < 4; ++j) {
            int col = bn0 + wn + j * 16 + fr;
            float bb = bias ? bias[col] : 0.0f;
            #pragma unroll
            for (int r = 0; r < 4; ++r) {
                int row = bm0 + wm + i * 16 + r0 + r;
                float v = acc[i][j][r] + bb;
                size_t off = (size_t)row * N + col;
                if (EPI == 1) v += C[off];
                C[off] = v;
            }
        }
}

// ---------------- split-bf16 MFMA GEMM, 128x64 tile (N=512 shapes; higher grid parallelism) ----
// 4 waves as 2x2, each 64x32 (4x2 frags). SPLITA=0: A single plane, 2 MFMAs per frag.
template<int EPI, int SPLITA>
__global__ __launch_bounds__(256) void gemm_n64(
    const u16* __restrict__ Ah, const u16* __restrict__ Al,
    const u16* __restrict__ Wh, const u16* __restrict__ Wl,
    const float* __restrict__ bias, float* __restrict__ C,
    int M, int N, int K) {
    __shared__ u16 As[SPLITA ? 2 : 1][128 * 40];
    __shared__ u16 Ws[2][64 * 40];
    int bx = blockIdx.x, by = blockIdx.y;
    swz2d(bx, by);
    const int bm0 = by * 128, bn0 = bx * 64;
    const int tid = threadIdx.x, lane = tid & 63, wid = tid >> 6;
    const int wm = (wid >> 1) * 64, wn = (wid & 1) * 32;
    const int fr = lane & 15, kg = (lane >> 4) * 8;
    f32x4 acc[4][2] = {};
    for (int k0 = 0; k0 < K; k0 += 32) {
        #pragma unroll
        for (int it = 0; it < 2; ++it) {
            int cc = it * 256 + tid;            // 0..511: A tile 128 rows x 4 chunks
            int row = cc >> 2, kc = (cc & 3) * 8;
            size_t ga = (size_t)(bm0 + row) * K + k0 + kc;
            *(uint4*)&As[0][row * 40 + kc] = *(const uint4*)&Ah[ga];
            if (SPLITA)
                *(uint4*)&As[1][row * 40 + kc] = *(const uint4*)&Al[ga];
        }
        {
            int row = tid >> 2, kc = (tid & 3) * 8;   // W tile 64 rows x 4 chunks
            size_t gw = (size_t)(bn0 + row) * K + k0 + kc;
            *(uint4*)&Ws[0][row * 40 + kc] = *(const uint4*)&Wh[gw];
            *(uint4*)&Ws[1][row * 40 + kc] = *(const uint4*)&Wl[gw];
        }
        __syncthreads();
        bf16x8 ah[4], al[4], bh[2], bl[2];
        #pragma unroll
        for (int i = 0; i < 4; ++i) {
            ah[i] = *(const bf16x8*)&As[0][(wm + i * 16 + fr) * 40 + kg];
            if (SPLITA)
                al[i] = *(const bf16x8*)&As[1][(wm + i * 16 + fr) * 40 + kg];
        }
        #pragma unroll
        for (int j = 0; j < 2; ++j) {
            bh[j] = *(const bf16x8*)&Ws[0][(wn + j * 16 + fr) * 40 + kg];
            bl[j] = *(const bf16x8*)&Ws[1][(wn + j * 16 + fr) * 40 + kg];
        }
        #pragma unroll
        for (int i = 0; i < 4; ++i)
            #pragma unroll
            for (int j = 0; j < 2; ++j) {
                acc[i][j] = __builtin_amdgcn_mfma_f32_16x16x32_bf16(ah[i], bh[j], acc[i][j], 0, 0, 0);
                acc[i][j] = __builtin_amdgcn_mfma_f32_16x16x32_bf16(ah[i], bl[j], acc[i][j], 0, 0, 0);
                if (SPLITA)
                    acc[i][j] = __builtin_amdgcn_mfma_f32_16x16x32_bf16(al[i], bh[j], acc[i][j], 0, 0, 0);
            }
        __syncthreads();
    }
    const int r0 = (lane >> 4) * 4;
    #pragma unroll
    for (int i = 0; i < 4; ++i)
        #pragma unroll
        for (int j = 0; j < 2; ++j) {
            int col = bn0 + wn + j * 16 + fr;
            float bb = bias ? bias[col] : 0.0f;
            #pragma unroll
            for (int r = 0; r < 4; ++r) {
                int row = bm0 + wm + i * 16 + r0 + r;
                float v = acc[i][j][r] + bb;
                size_t off = (size_t)row * N + col;
                if (EPI == 1) v += C[off];
                C[off] = v;
            }
        }
}

// ---------------- split-bf16 MFMA GEMM with fused GLU epilogue (writes single bf16 plane) ----
__global__ __launch_bounds__(256) void gemm_glu3(
    const u16* __restrict__ Ah, const u16* __restrict__ Al,
    const u16* __restrict__ Wh, const u16* __restrict__ Wl,
    const float* __restrict__ bias, u16* __restrict__ Hh) {
    const int K = DIM_;
    __shared__ u16 As[2][128 * 40];
    __shared__ u16 Ws[2][128 * 40];
    int bx = blockIdx.x, by = blockIdx.y;
    swz2d(bx, by);
    const int bm0 = by * 128, bn0 = bx * 64;
    const int tid = threadIdx.x, lane = tid & 63, wid = tid >> 6;
    const int wm = (wid >> 1) * 64, wn2 = (wid & 1) * 32;
    const int fr = lane & 15, kg = (lane >> 4) * 8;
    f32x4 acca[4][2] = {}, accg[4][2] = {};
    for (int k0 = 0; k0 < K; k0 += 32) {
        #pragma unroll
        for (int it = 0; it < 2; ++it) {
            int cc = it * 256 + tid;
            int row = cc >> 2, kc = (cc & 3) * 8;
            size_t ga = (size_t)(bm0 + row) * K + k0 + kc;
            int ng = (row < 64) ? (bn0 + row) : (FFH_ + bn0 + row - 64);
            size_t gw = (size_t)ng * K + k0 + kc;
            *(uint4*)&As[0][row * 40 + kc] = *(const uint4*)&Ah[ga];
            *(uint4*)&As[1][row * 40 + kc] = *(const uint4*)&Al[ga];
            *(uint4*)&Ws[0][row * 40 + kc] = *(const uint4*)&Wh[gw];
            *(uint4*)&Ws[1][row * 40 + kc] = *(const uint4*)&Wl[gw];
        }
        __syncthreads();
        bf16x8 ah[4], al[4], bah[2], bal[2], bgh[2], bgl[2];
        #pragma unroll
        for (int i = 0; i < 4; ++i) {
            ah[i] = *(const bf16x8*)&As[0][(wm + i * 16 + fr) * 40 + kg];
            al[i] = *(const bf16x8*)&As[1][(wm + i * 16 + fr) * 40 + kg];
        }
        #pragma unroll
        for (int j = 0; j < 2; ++j) {
            bah[j] = *(const bf16x8*)&Ws[0][(wn2 + j * 16 + fr) * 40 + kg];
            bal[j] = *(const bf16x8*)&Ws[1][(wn2 + j * 16 + fr) * 40 + kg];
            bgh[j] = *(const bf16x8*)&Ws[0][(64 + wn2 + j * 16 + fr) * 40 + kg];
            bgl[j] = *(const bf16x8*)&Ws[1][(64 + wn2 + j * 16 + fr) * 40 + kg];
        }
        #pragma unroll
        for (int i = 0; i < 4; ++i)
            #pragma unroll
            for (int j = 0; j < 2; ++j) {
                acca[i][j] = __builtin_amdgcn_mfma_f32_16x16x32_bf16(ah[i], bah[j], acca[i][j], 0, 0, 0);
                acca[i][j] = __builtin_amdgcn_mfma_f32_16x16x32_bf16(ah[i], bal[j], acca[i][j], 0, 0, 0);
                acca[i][j] = __builtin_amdgcn_mfma_f32_16x16x32_bf16(al[i], bah[j], acca[i][j], 0, 0, 0);
                accg[i][j] = __builtin_amdgcn_mfma_f32_16x16x32_bf16(ah[i], bgh[j], accg[i][j], 0, 0, 0);
                accg[i][j] = __builtin_amdgcn_mfma_f32_16x16x32_bf16(ah[i], bgl[j], accg[i][j], 0, 0, 0);
                accg[i][j] = __builtin_amdgcn_mfma_f32_16x16x32_bf16(al[i], bgh[j], accg[i][j], 0, 0, 0);
            }
        __syncthreads();
    }
    const int r0 = (lane >> 4) * 4;
    #pragma unroll
    for (int i = 0; i < 4; ++i)
        #pragma unroll
        for (int j = 0; j < 2; ++j) {
            int col = bn0 + wn2 + j * 16 + fr;
            float ba = bias[col], bg = bias[FFH_ + col];
            #pragma unroll
            for (int r = 0; r < 4; ++r) {
                int row = bm0 + wm + i * 16 + r0 + r;
                float av = acca[i][j][r] + ba;
                float gv = accg[i][j][r] + bg;
                float gl = 0.5f * gv * (1.0f + erff(gv * 0.70710678118654752f));
                Hh[(size_t)row * FFH_ + col] = bf16_rne(av * gl);
            }
        }
}

// ---------------- time attention: one wave per (b,h,n) ----------------
__global__ __launch_bounds__(64) void attn_time(
    const float* __restrict__ qkv, const float* __restrict__ fsin,
    const float* __restrict__ fcos, u16* __restrict__ Oh, u16* __restrict__ Ol) {
    int bid = blockIdx.x;               // b*HEADS_*N_ + h*N_ + n
    int n = bid % N_;
    int h = (bid / N_) % HEADS_;
    int b = bid / (N_ * HEADS_);
    int lane = threadIdx.x;             // = d
    __shared__ float qs[16][68], ks[16][68], vs[16][68], Pm[16][16];
    int parity = lane & 1;
    for (int f = 0; f < F_; ++f) {
        size_t base = (size_t)(b * S_ + f * N_ + n) * 1536 + h * 64;
        float qv = qkv[base + lane] * 0.125f;
        float kv = qkv[base + 512 + lane];
        float vv = qkv[base + 1024 + lane];
        float sn = fsin[f * 64 + lane], cs = fcos[f * 64 + lane];
        float qx = __shfl_xor(qv, 1);
        float kx = __shfl_xor(kv, 1);
        float qrot = parity ? qx : -qx;
        float krot = parity ? kx : -kx;
        qs[f][lane] = qv * cs + qrot * sn;
        ks[f][lane] = kv * cs + krot * sn;
        vs[f][lane] = vv;
    }
    __syncthreads();
    int j = lane & 15, r = lane >> 4;
    for (int rr = 0; rr < 4; ++rr) {
        int i = rr * 4 + r;
        float sacc = 0.f;
        #pragma unroll
        for (int d4 = 0; d4 < 16; ++d4) {
            float4 qa = *(const float4*)&qs[i][d4 * 4];
            float4 ka = *(const float4*)&ks[j][d4 * 4];
            sacc += qa.x*ka.x + qa.y*ka.y + qa.z*ka.z + qa.w*ka.w;
        }
        float mx = sacc;
        for (int off = 8; off; off >>= 1) mx = fmaxf(mx, __shfl_xor(mx, off));
        float p = expf(sacc - mx);
        float sum = p;
        for (int off = 8; off; off >>= 1) sum += __shfl_xor(sum, off);
        Pm[i][j] = p / sum;
    }
    __syncthreads();
    for (int i = 0; i < 16; ++i) {
        float acc = 0.f;
        #pragma unroll
        for (int jj = 0; jj < 16; ++jj) acc += Pm[i][jj] * vs[jj][lane];
        size_t ob = (size_t)(b * S_ + i * N_ + n) * 512 + h * 64 + lane;
        u16 hh = bf16_rne(acc);
        Oh[ob] = hh;
        Ol[ob] = bf16_rne(acc - bf16_f32(hh));
    }
}

// ---------------- spatial attention, MFMA flash version ----------------
__global__ __launch_bounds__(256, 2) void attn_space_mfma(
    const float* __restrict__ qkv, const float* __restrict__ isin,
    const float* __restrict__ icos, u16* __restrict__ Oh, u16* __restrict__ Ol) {
    int bid = blockIdx.x;               // b*HEADS_*F_ + h*F_ + f
    int f = bid % F_;
    int h = (bid / F_) % HEADS_;
    int b = bid / (F_ * HEADS_);
    const int tid = threadIdx.x, lane = tid & 63, wid = tid >> 6;
    const int fr = lane & 15, g = lane >> 4;        // kg = g*8
    __shared__ u16 Ksh[32][72], Ksl[32][72];        // [key][d]
    __shared__ u16 Vsh[64][40], Vsl[64][40];        // transposed [d][key]
    __shared__ u16 Psh[4][48][40], Psl[4][48][40];  // per-wave P pair
    const size_t rowbase = (size_t)b * S_ + (size_t)f * N_;

    bf16x8 qh[3][2], ql[3][2];
    #pragma unroll
    for (int i = 0; i < 3; ++i) {
        int n = wid * 48 + i * 16 + fr;
        #pragma unroll
        for (int ks = 0; ks < 2; ++ks) {
            int dbase = ks * 32 + g * 8;
            const float* qp = &qkv[(rowbase + n) * 1536 + h * 64 + dbase];
            float4 t0 = *(const float4*)qp;
            float4 t1 = *(const float4*)(qp + 4);
            float4 s0 = *(const float4*)&isin[n * 64 + dbase];
            float4 s1 = *(const float4*)&isin[n * 64 + dbase + 4];
            float4 c0 = *(const float4*)&icos[n * 64 + dbase];
            float4 c1 = *(const float4*)&icos[n * 64 + dbase + 4];
            float v[8];
            v[0] = (t0.x * c0.x - t0.y * s0.x) * 0.125f;
            v[1] = (t0.y * c0.y + t0.x * s0.y) * 0.125f;
            v[2] = (t0.z * c0.z - t0.w * s0.z) * 0.125f;
            v[3] = (t0.w * c0.w + t0.z * s0.w) * 0.125f;
            v[4] = (t1.x * c1.x - t1.y * s1.x) * 0.125f;
            v[5] = (t1.y * c1.y + t1.x * s1.y) * 0.125f;
            v[6] = (t1.z * c1.z - t1.w * s1.z) * 0.125f;
            v[7] = (t1.w * c1.w + t1.z * s1.w) * 0.125f;
            bf16x8 hh, ll;
            #pragma unroll
            for (int e = 0; e < 8; ++e) {
                u16 hb = bf16_rne(v[e]);
                hh[e] = (short)hb;
                ll[e] = (short)bf16_rne(v[e] - bf16_f32(hb));
            }
            qh[i][ks] = hh; ql[i][ks] = ll;
        }
    }

    float m[3][4], l[3][4];
    f32x4 oacc[3][4] = {};
    #pragma unroll
    for (int i = 0; i < 3; ++i)
        #pragma unroll
        for (int r = 0; r < 4; ++r) { m[i][r] = -3.0e38f; l[i][r] = 0.0f; }

    for (int kt = 0; kt < 6; ++kt) {            // keys kt*32 .. +32
        __syncthreads();
        #pragma unroll
        for (int it = 0; it < 2; ++it) {
            int c = it * 256 + tid;
            int kr = c >> 4, dseg = (c & 15) * 4;
            int nk = kt * 32 + kr;
            float4 t = *(const float4*)&qkv[(rowbase + nk) * 1536 + 512 + h * 64 + dseg];
            float4 sn = *(const float4*)&isin[nk * 64 + dseg];
            float4 cs = *(const float4*)&icos[nk * 64 + dseg];
            float v0 = t.x * cs.x - t.y * sn.x;
            float v1 = t.y * cs.y + t.x * sn.y;
            float v2 = t.z * cs.z - t.w * sn.z;
            float v3 = t.w * cs.w + t.z * sn.w;
            ushort4 hh, ll;
            hh.x = bf16_rne(v0); ll.x = bf16_rne(v0 - bf16_f32(hh.x));
            hh.y = bf16_rne(v1); ll.y = bf16_rne(v1 - bf16_f32(hh.y));
            hh.z = bf16_rne(v2); ll.z = bf16_rne(v2 - bf16_f32(hh.z));
            hh.w = bf16_rne(v3); ll.w = bf16_rne(v3 - bf16_f32(hh.w));
            *(ushort4*)&Ksh[kr][dseg] = hh;
            *(ushort4*)&Ksl[kr][dseg] = ll;
        }
        {
            int kr = tid & 31, ds8 = tid >> 5;
            const float* vp = &qkv[(rowbase + kt * 32 + kr) * 1536 + 1024 + h * 64 + ds8 * 8];
            float4 a = *(const float4*)vp;
            float4 b4 = *(const float4*)(vp + 4);
            float vv[8] = {a.x, a.y, a.z, a.w, b4.x, b4.y, b4.z, b4.w};
            #pragma unroll
            for (int e = 0; e < 8; ++e) {
                u16 hb = bf16_rne(vv[e]);
                Vsh[ds8 * 8 + e][kr] = hb;
                Vsl[ds8 * 8 + e][kr] = bf16_rne(vv[e] - bf16_f32(hb));
            }
        }
        __syncthreads();
        bf16x8 kbh[2][2], kbl[2][2];
        #pragma unroll
        for (int j = 0; j < 2; ++j)
            #pragma unroll
            for (int ks = 0; ks < 2; ++ks) {
                kbh[j][ks] = *(const bf16x8*)&Ksh[j * 16 + fr][ks * 32 + g * 8];
                kbl[j][ks] = *(const bf16x8*)&Ksl[j * 16 + fr][ks * 32 + g * 8];
            }
        f32x4 s[3][2] = {};
        #pragma unroll
        for (int i = 0; i < 3; ++i)
            #pragma unroll
            for (int j = 0; j < 2; ++j)
                #pragma unroll
                for (int ks = 0; ks < 2; ++ks) {
                    s[i][j] = __builtin_amdgcn_mfma_f32_16x16x32_bf16(qh[i][ks], kbh[j][ks], s[i][j], 0, 0, 0);
                    s[i][j] = __builtin_amdgcn_mfma_f32_16x16x32_bf16(qh[i][ks], kbl[j][ks], s[i][j], 0, 0, 0);
                    s[i][j] = __builtin_amdgcn_mfma_f32_16x16x32_bf16(ql[i][ks], kbh[j][ks], s[i][j], 0, 0, 0);
                }
        #pragma unroll
        for (int i = 0; i < 3; ++i) {
            float tmax[4], mn[4], corr[4], psum[4];
            #pragma unroll
            for (int r = 0; r < 4; ++r) tmax[r] = fmaxf(s[i][0][r], s[i][1][r]);
            #pragma unroll
            for (int off = 8; off; off >>= 1)
                #pragma unroll
                for (int r = 0; r < 4; ++r) tmax[r] = fmaxf(tmax[r], __shfl_xor(tmax[r], off));
            float p0[4], p1[4];
            #pragma unroll
            for (int r = 0; r < 4; ++r) {
                mn[r] = fmaxf(m[i][r], tmax[r]);
                corr[r] = expf(m[i][r] - mn[r]);
                p0[r] = expf(s[i][0][r] - mn[r]);
                p1[r] = expf(s[i][1][r] - mn[r]);
                psum[r] = p0[r] + p1[r];
                m[i][r] = mn[r];
            }
            #pragma unroll
            for (int off = 8; off; off >>= 1)
                #pragma unroll
                for (int r = 0; r < 4; ++r) psum[r] += __shfl_xor(psum[r], off);
            #pragma unroll
            for (int r = 0; r < 4; ++r) l[i][r] = l[i][r] * corr[r] + psum[r];
            #pragma unroll
            for (int dj = 0; dj < 4; ++dj)
                #pragma unroll
                for (int r = 0; r < 4; ++r) oacc[i][dj][r] *= corr[r];
            #pragma unroll
            for (int r = 0; r < 4; ++r) {
                int rl = i * 16 + g * 4 + r;
                u16 h0 = bf16_rne(p0[r]);
                Psh[wid][rl][fr]      = h0;
                Psl[wid][rl][fr]      = bf16_rne(p0[r] - bf16_f32(h0));
                u16 h1 = bf16_rne(p1[r]);
                Psh[wid][rl][16 + fr] = h1;
                Psl[wid][rl][16 + fr] = bf16_rne(p1[r] - bf16_f32(h1));
            }
        }
        bf16x8 pah[3], pal[3];
        #pragma unroll
        for (int i = 0; i < 3; ++i) {
            pah[i] = *(const bf16x8*)&Psh[wid][i * 16 + fr][g * 8];
            pal[i] = *(const bf16x8*)&Psl[wid][i * 16 + fr][g * 8];
        }
        bf16x8 vbh[4], vbl[4];
        #pragma unroll
        for (int dj = 0; dj < 4; ++dj) {
            vbh[dj] = *(const bf16x8*)&Vsh[dj * 16 + fr][g * 8];
            vbl[dj] = *(const bf16x8*)&Vsl[dj * 16 + fr][g * 8];
        }
        #pragma unroll
        for (int i = 0; i < 3; ++i)
            #pragma unroll
            for (int dj = 0; dj < 4; ++dj) {
                oacc[i][dj] = __builtin_amdgcn_mfma_f32_16x16x32_bf16(pah[i], vbh[dj], oacc[i][dj], 0, 0, 0);
                oacc[i][dj] = __builtin_amdgcn_mfma_f32_16x16x32_bf16(pah[i], vbl[dj], oacc[i][dj], 0, 0, 0);
                oacc[i][dj] = __builtin_amdgcn_mfma_f32_16x16x32_bf16(pal[i], vbh[dj], oacc[i][dj], 0, 0, 0);
            }
    }
    #pragma unroll
    for (int i = 0; i < 3; ++i) {
        #pragma unroll
        for (int r = 0; r < 4; ++r) {
            int row = wid * 48 + i * 16 + g * 4 + r;
            float invl = 1.0f / l[i][r];
            #pragma unroll
            for (int dj = 0; dj < 4; ++dj) {
                float v = oacc[i][dj][r] * invl;
                size_t ob = (rowbase + row) * 512 + h * 64 + dj * 16 + fr;
                u16 hh = bf16_rne(v);
                Oh[ob] = hh;
                Ol[ob] = bf16_rne(v - bf16_f32(hh));
            }
        }
    }
}

extern "C" void kernel_launch(void* const* d_in, const int* in_sizes, int n_in,
                              void* d_out, int out_size, void* d_ws, size_t ws_size,
                              hipStream_t stream) {
    (void)in_sizes; (void)n_in; (void)out_size; (void)ws_size;
    const float* video   = (const float*)d_in[0];
    const float* patch_w = (const float*)d_in[1];
    const float* patch_b = (const float*)d_in[2];
    const float* ln_t_g  = (const float*)d_in[3];
    const float* ln_t_b  = (const float*)d_in[4];
    const float* ln_s_g  = (const float*)d_in[5];
    const float* ln_s_b  = (const float*)d_in[6];
    const float* ln_f_g  = (const float*)d_in[7];
    const float* ln_f_b  = (const float*)d_in[8];
    const float* qkv_t   = (const float*)d_in[9];
    const float* out_t_w = (const float*)d_in[10];
    const float* out_t_b = (const float*)d_in[11];
    const float* qkv_s   = (const float*)d_in[12];
    const float* out_s_w = (const float*)d_in[13];
    const float* out_s_b = (const float*)d_in[14];
    const float* ff_w1   = (const float*)d_in[15];
    const float* ff_b1   = (const float*)d_in[16];
    const float* ff_w2   = (const float*)d_in[17];
    const float* ff_b2   = (const float*)d_in[18];

    float* x = (float*)d_out;                   // [12288][512] residual stream

    // ---- workspace layout (~104.5 MB) ----
    u16* wqt_h = (u16*)d_ws;                    // qkv_t^T pair [1536][512]
    u16* wqt_l = wqt_h + 1536 * 512;
    u16* wot_h = wqt_l + 1536 * 512;            // out_t^T pair [512][512]
    u16* wot_l = wot_h + 512 * 512;
    u16* wqs_h = wot_l + 512 * 512;
    u16* wqs_l = wqs_h + 1536 * 512;
    u16* wos_h = wqs_l + 1536 * 512;
    u16* wos_l = wos_h + 512 * 512;
    u16* wpt_h = wos_l + 512 * 512;             // patch_w^T pair [512][192]
    u16* wpt_l = wpt_h + 512 * PATCH_K;
    u16* y_h   = wpt_l + 512 * PATCH_K;         // activation pair [12288][512]; o aliases y
    u16* y_l   = y_h + (size_t)ROWS * DIM_;
    float* big2 = (float*)(y_l + (size_t)ROWS * DIM_);  // 75.5 MB multi-use region
    float* qkv  = big2;                                  // attn phase: [12288][1536] fp32
    u16* vp_h = (u16*)big2;                              // patch pre pair [12288][192]
    u16* vp_l = vp_h + (size_t)ROWS * PATCH_K;
    u16* h2    = (u16*)big2;                             // FF phase: [12288][2048] single plane
    u16* f1t_h = h2 + (size_t)ROWS * FFH_;               // ff_w1^T pair [4096][512]
    u16* f1t_l = f1t_h + 4096 * 512;
    u16* f2t_h = f1t_l + 4096 * 512;                     // ff_w2^T pair [512][2048]
    u16* f2t_l = f2t_h + 512 * FFH_;
    float* fsin = (float*)((char*)big2 + (size_t)ROWS * 1536 * 4);
    float* fcos = fsin + F_ * 64;
    float* isin = fcos + F_ * 64;
    float* icos = isin + N_ * 64;
    u16* o_h = y_h;
    u16* o_l = y_l;

    rope_tables<<<2, 256, 0, stream>>>(fsin, fcos, isin, icos);

    // ---- patch embed ----
    convert_wt<<<dim3(DIM_ / 32, PATCH_K / 32), 256, 0, stream>>>(patch_w, wpt_h, wpt_l, PATCH_K, DIM_);
    rearrange_video_p<<<(ROWS * PATCH_K + 255) / 256, 256, 0, stream>>>(video, vp_h, vp_l);
    gemm_n64<0, 1><<<dim3(DIM_ / 64, ROWS / 128), 256, 0, stream>>>(
        vp_h, vp_l, wpt_h, wpt_l, patch_b, x, ROWS, DIM_, PATCH_K);

    for (int l = 0; l < 4; ++l) {
        convert_wt<<<dim3(1536 / 32, DIM_ / 32), 256, 0, stream>>>(
            qkv_t + (size_t)l * DIM_ * 1536, wqt_h, wqt_l, DIM_, 1536);
        convert_wt<<<dim3(DIM_ / 32, DIM_ / 32), 256, 0, stream>>>(
            out_t_w + (size_t)l * DIM_ * DIM_, wot_h, wot_l, DIM_, DIM_);
        convert_wt<<<dim3(1536 / 32, DIM_ / 32), 256, 0, stream>>>(
            qkv_s + (size_t)l * DIM_ * 1536, wqs_h, wqs_l, DIM_, 1536);
        convert_wt<<<dim3(DIM_ / 32, DIM_ / 32), 256, 0, stream>>>(
            out_s_w + (size_t)l * DIM_ * DIM_, wos_h, wos_l, DIM_, DIM_);

        // ---- time attention ----
        layernorm_p<<<ROWS, 64, 0, stream>>>(x, ln_t_g + l * DIM_, ln_t_b + l * DIM_, y_h, y_l);
        gemm_mfma3<0><<<dim3(1536 / 128, ROWS / 128), 256, 0, stream>>>(
            y_h, y_l, wqt_h, wqt_l, nullptr, qkv, ROWS, 1536, DIM_);
        attn_time<<<B_ * HEADS_ * N_, 64, 0, stream>>>(qkv, fsin, fcos, o_h, o_l);
        gemm_n64<1, 1><<<dim3(DIM_ / 64, ROWS / 128), 256, 0, stream>>>(
            o_h, o_l, wot_h, wot_l, out_t_b + l * DIM_, x, ROWS, DIM_, DIM_);

        // ---- spatial attention (MFMA flash) ----
        layernorm_p<<<ROWS, 64, 0, stream>>>(x, ln_s_g + l * DIM_, ln_s_b + l * DIM_, y_h, y_l);
        gemm_mfma3<0><<<dim3(1536 / 128, ROWS / 128), 256, 0, stream>>>(
            y_h, y_l, wqs_h, wqs_l, nullptr, qkv, ROWS, 1536, DIM_);
        attn_space_mfma<<<B_ * HEADS_ * F_, 256, 0, stream>>>(qkv, isin, icos, o_h, o_l);
        gemm_n64<1, 1><<<dim3(DIM_ / 64, ROWS / 128), 256, 0, stream>>>(
            o_h, o_l, wos_h, wos_l, out_s_b + l * DIM_, x, ROWS, DIM_, DIM_);

        // ---- FF with fused GLU, full-M (h2 single bf16 plane) ----
        convert_wt<<<dim3(4096 / 32, DIM_ / 32), 256, 0, stream>>>(
            ff_w1 + (size_t)l * DIM_ * 2 * FFH_, f1t_h, f1t_l, DIM_, 4096);
        convert_wt<<<dim3(DIM_ / 32, FFH_ / 32), 256, 0, stream>>>(
            ff_w2 + (size_t)l * FFH_ * DIM_, f2t_h, f2t_l, FFH_, DIM_);
        layernorm_p<<<ROWS, 64, 0, stream>>>(x, ln_f_g + l * DIM_, ln_f_b + l * DIM_, y_h, y_l);
        gemm_glu3<<<dim3(FFH_ / 64, ROWS / 128), 256, 0, stream>>>(
            y_h, y_l, f1t_h, f1t_l, ff_b1 + l * 2 * FFH_, h2);
        gemm_n64<1, 0><<<dim3(DIM_ / 64, ROWS / 128), 256, 0, stream>>>(
            h2, nullptr, f2t_h, f2t_l, ff_b2 + l * DIM_, x, ROWS, DIM_, FFH_);
    }
}

// Round 7
// 2534.239 us; speedup vs baseline: 3.0581x; 1.0032x over previous
//
#include <hip/hip_runtime.h>
#include <math.h>

#define B_ 4
#define F_ 16
#define HP_ 12
#define WP_ 16
#define N_ 192            // HP*WP
#define S_ (F_*N_)        // 3072 tokens per batch
#define ROWS (B_*S_)      // 12288
#define DIM_ 512
#define HEADS_ 8
#define DH_ 64
#define FFH_ 2048
#define PATCH_K 192
#define PI_F 3.14159265358979323846f

typedef unsigned short u16;
typedef __attribute__((ext_vector_type(8))) short bf16x8;
typedef __attribute__((ext_vector_type(4))) float f32x4;

__device__ __forceinline__ u16 bf16_rne(float f) {
    unsigned int u = __float_as_uint(f);
    u += 0x7FFFu + ((u >> 16) & 1u);
    return (u16)(u >> 16);
}
__device__ __forceinline__ float bf16_f32(u16 h) {
    return __uint_as_float(((unsigned int)h) << 16);
}

// Column-major XCD-chunked swizzle: each XCD owns a contiguous strip of
// N-columns (bx) across the full M sweep -> its W slab stays L2-resident
// while A streams from L3. Bijective when nwg % 8 == 0 (all our grids).
__device__ __forceinline__ void swz_col(int& bx, int& by) {
    int gx = gridDim.x, gy = gridDim.y;
    int nwg = gx * gy;
    int id = by * gx + bx;
    if ((nwg & 7) == 0) {
        int cpx = nwg >> 3;
        int t = (id & 7) * cpx + (id >> 3);   // contiguous logical range per XCD
        bx = t / gy;                          // bx slowest: column-major
        by = t % gy;
    }
}

// ---------------- RoPE tables ----------------
__global__ void rope_tables(float* __restrict__ fsin, float* __restrict__ fcos,
                            float* __restrict__ isin, float* __restrict__ icos) {
    int tid = blockIdx.x * blockDim.x + threadIdx.x;
    int stride = gridDim.x * blockDim.x;
    for (int idx = tid; idx < F_ * 64; idx += stride) {
        int f = idx >> 6, j = idx & 63;
        int i = j & 31;
        float inv = powf(10000.0f, -((float)i) / 32.0f);
        float fr = (float)f * inv;
        fsin[idx] = sinf(fr);
        fcos[idx] = cosf(fr);
    }
    for (int idx = tid; idx < N_ * 32; idx += stride) {
        int n = idx >> 5, k = idx & 31;
        int h = n / WP_, w = n % WP_;
        float scale = exp2f((float)(k & 15) * (log2f(5.0f) / 15.0f));
        float pos = (k < 16) ? (-1.0f + 2.0f * (float)h / (float)(HP_ - 1))
                             : (-1.0f + 2.0f * (float)w / (float)(WP_ - 1));
        float val = pos * scale * PI_F;
        float sv = sinf(val), cv = cosf(val);
        isin[n * 64 + 2 * k] = sv; isin[n * 64 + 2 * k + 1] = sv;
        icos[n * 64 + 2 * k] = cv; icos[n * 64 + 2 * k + 1] = cv;
    }
}

// ---------------- patch rearrange -> bf16 hi/lo planes ----------------
__global__ void rearrange_video_p(const float* __restrict__ video,
                                  u16* __restrict__ Vh, u16* __restrict__ Vl) {
    int t = blockIdx.x * blockDim.x + threadIdx.x;
    const int total = ROWS * PATCH_K;
    if (t >= total) return;
    int col = t % PATCH_K;
    int row = t / PATCH_K;
    int c  = col % 3;
    int pp = col / 3;
    int pi = pp >> 3, pj = pp & 7;
    int n  = row % N_;
    int bf = row / N_;
    int hp = n / WP_, wp = n % WP_;
    int hidx = hp * 8 + pi, widx = wp * 8 + pj;
    float f = video[((size_t)(bf * 3 + c) * 96 + hidx) * 128 + widx];
    u16 h = bf16_rne(f);
    Vh[t] = h;
    Vl[t] = bf16_rne(f - bf16_f32(h));
}

// ---------------- weight transpose + split: W[K][N] f32 -> Wt_hi/lo [N][K] bf16 ----------------
__global__ __launch_bounds__(256) void convert_wt(
    const float* __restrict__ W, u16* __restrict__ Wh, u16* __restrict__ Wl,
    int K, int N) {
    __shared__ float tile[32][33];
    int nb = blockIdx.x * 32, kb = blockIdx.y * 32;
    int tx = threadIdx.x & 31, ty = threadIdx.x >> 5;   // ty 0..7
    #pragma unroll
    for (int i = 0; i < 32; i += 8)
        tile[ty + i][tx] = W[(size_t)(kb + ty + i) * N + nb + tx];
    __syncthreads();
    #pragma unroll
    for (int i = 0; i < 32; i += 8) {
        int n = nb + ty + i, k = kb + tx;
        float f = tile[tx][ty + i];
        u16 h = bf16_rne(f);
        Wh[(size_t)n * K + k] = h;
        Wl[(size_t)n * K + k] = bf16_rne(f - bf16_f32(h));
    }
}

// ---------------- LayerNorm -> bf16 hi(/lo) planes (Yl may be null) ----------------
__global__ __launch_bounds__(64) void layernorm_p(
    const float* __restrict__ x, const float* __restrict__ g,
    const float* __restrict__ b, u16* __restrict__ Yh, u16* __restrict__ Yl) {
    int row = blockIdx.x;
    int lane = threadIdx.x;
    const float* xr = x + (size_t)row * DIM_;
    float4 v0 = *(const float4*)&xr[lane * 8];
    float4 v1 = *(const float4*)&xr[lane * 8 + 4];
    float s  = v0.x + v0.y + v0.z + v0.w + v1.x + v1.y + v1.z + v1.w;
    float sq = v0.x*v0.x + v0.y*v0.y + v0.z*v0.z + v0.w*v0.w
             + v1.x*v1.x + v1.y*v1.y + v1.z*v1.z + v1.w*v1.w;
    for (int off = 32; off; off >>= 1) { s += __shfl_xor(s, off); sq += __shfl_xor(sq, off); }
    float mu  = s * (1.0f / 512.0f);
    float var = sq * (1.0f / 512.0f) - mu * mu;
    float inv = rsqrtf(var + 1e-5f);
    float4 g0 = *(const float4*)&g[lane * 8];
    float4 g1 = *(const float4*)&g[lane * 8 + 4];
    float4 b0 = *(const float4*)&b[lane * 8];
    float4 b1 = *(const float4*)&b[lane * 8 + 4];
    float o[8];
    o[0] = (v0.x - mu) * inv * g0.x + b0.x;
    o[1] = (v0.y - mu) * inv * g0.y + b0.y;
    o[2] = (v0.z - mu) * inv * g0.z + b0.z;
    o[3] = (v0.w - mu) * inv * g0.w + b0.w;
    o[4] = (v1.x - mu) * inv * g1.x + b1.x;
    o[5] = (v1.y - mu) * inv * g1.y + b1.y;
    o[6] = (v1.z - mu) * inv * g1.z + b1.z;
    o[7] = (v1.w - mu) * inv * g1.w + b1.w;
    size_t ro = (size_t)row * DIM_ + lane * 8;
    ushort4 h0, h1;
    h0.x = bf16_rne(o[0]); h0.y = bf16_rne(o[1]);
    h0.z = bf16_rne(o[2]); h0.w = bf16_rne(o[3]);
    h1.x = bf16_rne(o[4]); h1.y = bf16_rne(o[5]);
    h1.z = bf16_rne(o[6]); h1.w = bf16_rne(o[7]);
    *(ushort4*)&Yh[ro]     = h0;
    *(ushort4*)&Yh[ro + 4] = h1;
    if (Yl) {
        ushort4 l0, l1;
        l0.x = bf16_rne(o[0] - bf16_f32(h0.x));
        l0.y = bf16_rne(o[1] - bf16_f32(h0.y));
        l0.z = bf16_rne(o[2] - bf16_f32(h0.z));
        l0.w = bf16_rne(o[3] - bf16_f32(h0.w));
        l1.x = bf16_rne(o[4] - bf16_f32(h1.x));
        l1.y = bf16_rne(o[5] - bf16_f32(h1.y));
        l1.z = bf16_rne(o[6] - bf16_f32(h1.z));
        l1.w = bf16_rne(o[7] - bf16_f32(h1.w));
        *(ushort4*)&Yl[ro]     = l0;
        *(ushort4*)&Yl[ro + 4] = l1;
    }
}

// ---------------- split-bf16 MFMA GEMM, 128x128 tile (qkv, N=1536) ----------------
template<int EPI>
__global__ __launch_bounds__(256) void gemm_mfma3(
    const u16* __restrict__ Ah, const u16* __restrict__ Al,
    const u16* __restrict__ Wh, const u16* __restrict__ Wl,
    const float* __restrict__ bias, float* __restrict__ C,
    int M, int N, int K) {
    __shared__ u16 As[2][128 * 40];
    __shared__ u16 Ws[2][128 * 40];
    int bx = blockIdx.x, by = blockIdx.y;
    swz_col(bx, by);
    const int bm0 = by * 128, bn0 = bx * 128;
    const int tid = threadIdx.x, lane = tid & 63, wid = tid >> 6;
    const int wm = (wid >> 1) * 64, wn = (wid & 1) * 64;
    const int fr = lane & 15, kg = (lane >> 4) * 8;
    f32x4 acc[4][4] = {};
    for (int k0 = 0; k0 < K; k0 += 32) {
        #pragma unroll
        for (int it = 0; it < 2; ++it) {
            int cc = it * 256 + tid;            // 0..511
            int row = cc >> 2, kc = (cc & 3) * 8;
            size_t ga = (size_t)(bm0 + row) * K + k0 + kc;
            size_t gw = (size_t)(bn0 + row) * K + k0 + kc;
            *(uint4*)&As[0][row * 40 + kc] = *(const uint4*)&Ah[ga];
            *(uint4*)&As[1][row * 40 + kc] = *(const uint4*)&Al[ga];
            *(uint4*)&Ws[0][row * 40 + kc] = *(const uint4*)&Wh[gw];
            *(uint4*)&Ws[1][row * 40 + kc] = *(const uint4*)&Wl[gw];
        }
        __syncthreads();
        bf16x8 ah[4], al[4], bh[4], bl[4];
        #pragma unroll
        for (int i = 0; i < 4; ++i) {
            ah[i] = *(const bf16x8*)&As[0][(wm + i * 16 + fr) * 40 + kg];
            al[i] = *(const bf16x8*)&As[1][(wm + i * 16 + fr) * 40 + kg];
            bh[i] = *(const bf16x8*)&Ws[0][(wn + i * 16 + fr) * 40 + kg];
            bl[i] = *(const bf16x8*)&Ws[1][(wn + i * 16 + fr) * 40 + kg];
        }
        #pragma unroll
        for (int i = 0; i < 4; ++i)
            #pragma unroll
            for (int j = 0; j < 4; ++j) {
                acc[i][j] = __builtin_amdgcn_mfma_f32_16x16x32_bf16(ah[i], bh[j], acc[i][j], 0, 0, 0);
                acc[i][j] = __builtin_amdgcn_mfma_f32_16x16x32_bf16(ah[i], bl[j], acc[i][j], 0, 0, 0);
                acc[i][j] = __builtin_amdgcn_mfma_f32_16x16x32_bf16(al[i], bh[j], acc[i][j], 0, 0, 0);
            }
        __syncthreads();
    }
    const int r0 = (lane >> 4) * 4;
    #pragma unroll
    for (int i = 0; i < 4; ++i)
        #pragma unroll
        for (int j = 0; j < 4; ++j) {
            int col = bn0 + wn + j * 16 + fr;
            float bb = bias ? bias[col] : 0.0f;
            #pragma unroll
            for (int r = 0; r < 4; ++r) {
                int row = bm0 + wm + i * 16 + r0 + r;
                float v = acc[i][j][r] + bb;
                size_t off = (size_t)row * N + col;
                if (EPI == 1) v += C[off];
                C[off] = v;
            }
        }
}

// ---------------- split-bf16 MFMA GEMM, 128x64 tile (N=512 shapes) ----------------
template<int EPI, int SPLITA>
__global__ __launch_bounds__(256) void gemm_n64(
    const u16* __restrict__ Ah, const u16* __restrict__ Al,
    const u16* __restrict__ Wh, const u16* __restrict__ Wl,
    const float* __restrict__ bias, float* __restrict__ C,
    int M, int N, int K) {
    __shared__ u16 As[SPLITA ? 2 : 1][128 * 40];
    __shared__ u16 Ws[2][64 * 40];
    int bx = blockIdx.x, by = blockIdx.y;
    swz_col(bx, by);
    const int bm0 = by * 128, bn0 = bx * 64;
    const int tid = threadIdx.x, lane = tid & 63, wid = tid >> 6;
    const int wm = (wid >> 1) * 64, wn = (wid & 1) * 32;
    const int fr = lane & 15, kg = (lane >> 4) * 8;
    f32x4 acc[4][2] = {};
    for (int k0 = 0; k0 < K; k0 += 32) {
        #pragma unroll
        for (int it = 0; it < 2; ++it) {
            int cc = it * 256 + tid;            // A tile: 128 rows x 4 chunks
            int row = cc >> 2, kc = (cc & 3) * 8;
            size_t ga = (size_t)(bm0 + row) * K + k0 + kc;
            *(uint4*)&As[0][row * 40 + kc] = *(const uint4*)&Ah[ga];
            if (SPLITA)
                *(uint4*)&As[1][row * 40 + kc] = *(const uint4*)&Al[ga];
        }
        {
            int row = tid >> 2, kc = (tid & 3) * 8;   // W tile: 64 rows x 4 chunks
            size_t gw = (size_t)(bn0 + row) * K + k0 + kc;
            *(uint4*)&Ws[0][row * 40 + kc] = *(const uint4*)&Wh[gw];
            *(uint4*)&Ws[1][row * 40 + kc] = *(const uint4*)&Wl[gw];
        }
        __syncthreads();
        bf16x8 ah[4], al[4], bh[2], bl[2];
        #pragma unroll
        for (int i = 0; i < 4; ++i) {
            ah[i] = *(const bf16x8*)&As[0][(wm + i * 16 + fr) * 40 + kg];
            if (SPLITA)
                al[i] = *(const bf16x8*)&As[1][(wm + i * 16 + fr) * 40 + kg];
        }
        #pragma unroll
        for (int j = 0; j < 2; ++j) {
            bh[j] = *(const bf16x8*)&Ws[0][(wn + j * 16 + fr) * 40 + kg];
            bl[j] = *(const bf16x8*)&Ws[1][(wn + j * 16 + fr) * 40 + kg];
        }
        #pragma unroll
        for (int i = 0; i < 4; ++i)
            #pragma unroll
            for (int j = 0; j < 2; ++j) {
                acc[i][j] = __builtin_amdgcn_mfma_f32_16x16x32_bf16(ah[i], bh[j], acc[i][j], 0, 0, 0);
                acc[i][j] = __builtin_amdgcn_mfma_f32_16x16x32_bf16(ah[i], bl[j], acc[i][j], 0, 0, 0);
                if (SPLITA)
                    acc[i][j] = __builtin_amdgcn_mfma_f32_16x16x32_bf16(al[i], bh[j], acc[i][j], 0, 0, 0);
            }
        __syncthreads();
    }
    const int r0 = (lane >> 4) * 4;
    #pragma unroll
    for (int i = 0; i < 4; ++i)
        #pragma unroll
        for (int j = 0; j < 2; ++j) {
            int col = bn0 + wn + j * 16 + fr;
            float bb = bias ? bias[col] : 0.0f;
            #pragma unroll
            for (int r = 0; r < 4; ++r) {
                int row = bm0 + wm + i * 16 + r0 + r;
                float v = acc[i][j][r] + bb;
                size_t off = (size_t)row * N + col;
                if (EPI == 1) v += C[off];
                C[off] = v;
            }
        }
}

// ---------------- GLU GEMM: A single hi plane (split-2), W pair; bf16 out ----------------
__global__ __launch_bounds__(256) void gemm_glu3(
    const u16* __restrict__ Ah,
    const u16* __restrict__ Wh, const u16* __restrict__ Wl,
    const float* __restrict__ bias, u16* __restrict__ Hh) {
    const int K = DIM_;
    __shared__ u16 As[128 * 40];
    __shared__ u16 Ws[2][128 * 40];
    int bx = blockIdx.x, by = blockIdx.y;
    swz_col(bx, by);
    const int bm0 = by * 128, bn0 = bx * 64;
    const int tid = threadIdx.x, lane = tid & 63, wid = tid >> 6;
    const int wm = (wid >> 1) * 64, wn2 = (wid & 1) * 32;
    const int fr = lane & 15, kg = (lane >> 4) * 8;
    f32x4 acca[4][2] = {}, accg[4][2] = {};
    for (int k0 = 0; k0 < K; k0 += 32) {
        #pragma unroll
        for (int it = 0; it < 2; ++it) {
            int cc = it * 256 + tid;
            int row = cc >> 2, kc = (cc & 3) * 8;
            size_t ga = (size_t)(bm0 + row) * K + k0 + kc;
            int ng = (row < 64) ? (bn0 + row) : (FFH_ + bn0 + row - 64);
            size_t gw = (size_t)ng * K + k0 + kc;
            *(uint4*)&As[row * 40 + kc] = *(const uint4*)&Ah[ga];
            *(uint4*)&Ws[0][row * 40 + kc] = *(const uint4*)&Wh[gw];
            *(uint4*)&Ws[1][row * 40 + kc] = *(const uint4*)&Wl[gw];
        }
        __syncthreads();
        bf16x8 ah[4], bah[2], bal[2], bgh[2], bgl[2];
        #pragma unroll
        for (int i = 0; i < 4; ++i)
            ah[i] = *(const bf16x8*)&As[(wm + i * 16 + fr) * 40 + kg];
        #pragma unroll
        for (int j = 0; j < 2; ++j) {
            bah[j] = *(const bf16x8*)&Ws[0][(wn2 + j * 16 + fr) * 40 + kg];
            bal[j] = *(const bf16x8*)&Ws[1][(wn2 + j * 16 + fr) * 40 + kg];
            bgh[j] = *(const bf16x8*)&Ws[0][(64 + wn2 + j * 16 + fr) * 40 + kg];
            bgl[j] = *(const bf16x8*)&Ws[1][(64 + wn2 + j * 16 + fr) * 40 + kg];
        }
        #pragma unroll
        for (int i = 0; i < 4; ++i)
            #pragma unroll
            for (int j = 0; j < 2; ++j) {
                acca[i][j] = __builtin_amdgcn_mfma_f32_16x16x32_bf16(ah[i], bah[j], acca[i][j], 0, 0, 0);
                acca[i][j] = __builtin_amdgcn_mfma_f32_16x16x32_bf16(ah[i], bal[j], acca[i][j], 0, 0, 0);
                accg[i][j] = __builtin_amdgcn_mfma_f32_16x16x32_bf16(ah[i], bgh[j], accg[i][j], 0, 0, 0);
                accg[i][j] = __builtin_amdgcn_mfma_f32_16x16x32_bf16(ah[i], bgl[j], accg[i][j], 0, 0, 0);
            }
        __syncthreads();
    }
    const int r0 = (lane >> 4) * 4;
    #pragma unroll
    for (int i = 0; i < 4; ++i)
        #pragma unroll
        for (int j = 0; j < 2; ++j) {
            int col = bn0 + wn2 + j * 16 + fr;
            float ba = bias[col], bg = bias[FFH_ + col];
            #pragma unroll
            for (int r = 0; r < 4; ++r) {
                int row = bm0 + wm + i * 16 + r0 + r;
                float av = acca[i][j][r] + ba;
                float gv = accg[i][j][r] + bg;
                float gl = 0.5f * gv * (1.0f + erff(gv * 0.70710678118654752f));
                Hh[(size_t)row * FFH_ + col] = bf16_rne(av * gl);
            }
        }
}

// ---------------- time attention: one wave per (b,h,n) ----------------
__global__ __launch_bounds__(64) void attn_time(
    const float* __restrict__ qkv, const float* __restrict__ fsin,
    const float* __restrict__ fcos, u16* __restrict__ Oh, u16* __restrict__ Ol) {
    int bid = blockIdx.x;               // b*HEADS_*N_ + h*N_ + n
    int n = bid % N_;
    int h = (bid / N_) % HEADS_;
    int b = bid / (N_ * HEADS_);
    int lane = threadIdx.x;             // = d
    __shared__ float qs[16][68], ks[16][68], vs[16][68], Pm[16][16];
    int parity = lane & 1;
    for (int f = 0; f < F_; ++f) {
        size_t base = (size_t)(b * S_ + f * N_ + n) * 1536 + h * 64;
        float qv = qkv[base + lane] * 0.125f;
        float kv = qkv[base + 512 + lane];
        float vv = qkv[base + 1024 + lane];
        float sn = fsin[f * 64 + lane], cs = fcos[f * 64 + lane];
        float qx = __shfl_xor(qv, 1);
        float kx = __shfl_xor(kv, 1);
        float qrot = parity ? qx : -qx;
        float krot = parity ? kx : -kx;
        qs[f][lane] = qv * cs + qrot * sn;
        ks[f][lane] = kv * cs + krot * sn;
        vs[f][lane] = vv;
    }
    __syncthreads();
    int j = lane & 15, r = lane >> 4;
    for (int rr = 0; rr < 4; ++rr) {
        int i = rr * 4 + r;
        float sacc = 0.f;
        #pragma unroll
        for (int d4 = 0; d4 < 16; ++d4) {
            float4 qa = *(const float4*)&qs[i][d4 * 4];
            float4 ka = *(const float4*)&ks[j][d4 * 4];
            sacc += qa.x*ka.x + qa.y*ka.y + qa.z*ka.z + qa.w*ka.w;
        }
        float mx = sacc;
        for (int off = 8; off; off >>= 1) mx = fmaxf(mx, __shfl_xor(mx, off));
        float p = expf(sacc - mx);
        float sum = p;
        for (int off = 8; off; off >>= 1) sum += __shfl_xor(sum, off);
        Pm[i][j] = p / sum;
    }
    __syncthreads();
    for (int i = 0; i < 16; ++i) {
        float acc = 0.f;
        #pragma unroll
        for (int jj = 0; jj < 16; ++jj) acc += Pm[i][jj] * vs[jj][lane];
        size_t ob = (size_t)(b * S_ + i * N_ + n) * 512 + h * 64 + lane;
        u16 hh = bf16_rne(acc);
        Oh[ob] = hh;
        Ol[ob] = bf16_rne(acc - bf16_f32(hh));
    }
}

// ---------------- spatial attention, MFMA flash version ----------------
__global__ __launch_bounds__(256, 2) void attn_space_mfma(
    const float* __restrict__ qkv, const float* __restrict__ isin,
    const float* __restrict__ icos, u16* __restrict__ Oh, u16* __restrict__ Ol) {
    int bid = blockIdx.x;               // b*HEADS_*F_ + h*F_ + f
    int f = bid % F_;
    int h = (bid / F_) % HEADS_;
    int b = bid / (F_ * HEADS_);
    const int tid = threadIdx.x, lane = tid & 63, wid = tid >> 6;
    const int fr = lane & 15, g = lane >> 4;        // kg = g*8
    __shared__ u16 Ksh[32][72], Ksl[32][72];        // [key][d]
    __shared__ u16 Vsh[64][40], Vsl[64][40];        // transposed [d][key]
    __shared__ u16 Psh[4][48][40], Psl[4][48][40];  // per-wave P pair
    const size_t rowbase = (size_t)b * S_ + (size_t)f * N_;

    bf16x8 qh[3][2], ql[3][2];
    #pragma unroll
    for (int i = 0; i < 3; ++i) {
        int n = wid * 48 + i * 16 + fr;
        #pragma unroll
        for (int ks = 0; ks < 2; ++ks) {
            int dbase = ks * 32 + g * 8;
            const float* qp = &qkv[(rowbase + n) * 1536 + h * 64 + dbase];
            float4 t0 = *(const float4*)qp;
            float4 t1 = *(const float4*)(qp + 4);
            float4 s0 = *(const float4*)&isin[n * 64 + dbase];
            float4 s1 = *(const float4*)&isin[n * 64 + dbase + 4];
            float4 c0 = *(const float4*)&icos[n * 64 + dbase];
            float4 c1 = *(const float4*)&icos[n * 64 + dbase + 4];
            float v[8];
            v[0] = (t0.x * c0.x - t0.y * s0.x) * 0.125f;
            v[1] = (t0.y * c0.y + t0.x * s0.y) * 0.125f;
            v[2] = (t0.z * c0.z - t0.w * s0.z) * 0.125f;
            v[3] = (t0.w * c0.w + t0.z * s0.w) * 0.125f;
            v[4] = (t1.x * c1.x - t1.y * s1.x) * 0.125f;
            v[5] = (t1.y * c1.y + t1.x * s1.y) * 0.125f;
            v[6] = (t1.z * c1.z - t1.w * s1.z) * 0.125f;
            v[7] = (t1.w * c1.w + t1.z * s1.w) * 0.125f;
            bf16x8 hh, ll;
            #pragma unroll
            for (int e = 0; e < 8; ++e) {
                u16 hb = bf16_rne(v[e]);
                hh[e] = (short)hb;
                ll[e] = (short)bf16_rne(v[e] - bf16_f32(hb));
            }
            qh[i][ks] = hh; ql[i][ks] = ll;
        }
    }

    float m[3][4], l[3][4];
    f32x4 oacc[3][4] = {};
    #pragma unroll
    for (int i = 0; i < 3; ++i)
        #pragma unroll
        for (int r = 0; r < 4; ++r) { m[i][r] = -3.0e38f; l[i][r] = 0.0f; }

    for (int kt = 0; kt < 6; ++kt) {            // keys kt*32 .. +32
        __syncthreads();
        #pragma unroll
        for (int it = 0; it < 2; ++it) {
            int c = it * 256 + tid;
            int kr = c >> 4, dseg = (c & 15) * 4;
            int nk = kt * 32 + kr;
            float4 t = *(const float4*)&qkv[(rowbase + nk) * 1536 + 512 + h * 64 + dseg];
            float4 sn = *(const float4*)&isin[nk * 64 + dseg];
            float4 cs = *(const float4*)&icos[nk * 64 + dseg];
            float v0 = t.x * cs.x - t.y * sn.x;
            float v1 = t.y * cs.y + t.x * sn.y;
            float v2 = t.z * cs.z - t.w * sn.z;
            float v3 = t.w * cs.w + t.z * sn.w;
            ushort4 hh, ll;
            hh.x = bf16_rne(v0); ll.x = bf16_rne(v0 - bf16_f32(hh.x));
            hh.y = bf16_rne(v1); ll.y = bf16_rne(v1 - bf16_f32(hh.y));
            hh.z = bf16_rne(v2); ll.z = bf16_rne(v2 - bf16_f32(hh.z));
            hh.w = bf16_rne(v3); ll.w = bf16_rne(v3 - bf16_f32(hh.w));
            *(ushort4*)&Ksh[kr][dseg] = hh;
            *(ushort4*)&Ksl[kr][dseg] = ll;
        }
        {
            int kr = tid & 31, ds8 = tid >> 5;
            const float* vp = &qkv[(rowbase + kt * 32 + kr) * 1536 + 1024 + h * 64 + ds8 * 8];
            float4 a = *(const float4*)vp;
            float4 b4 = *(const float4*)(vp + 4);
            float vv[8] = {a.x, a.y, a.z, a.w, b4.x, b4.y, b4.z, b4.w};
            #pragma unroll
            for (int e = 0; e < 8; ++e) {
                u16 hb = bf16_rne(vv[e]);
                Vsh[ds8 * 8 + e][kr] = hb;
                Vsl[ds8 * 8 + e][kr] = bf16_rne(vv[e] - bf16_f32(hb));
            }
        }
        __syncthreads();
        bf16x8 kbh[2][2], kbl[2][2];
        #pragma unroll
        for (int j = 0; j < 2; ++j)
            #pragma unroll
            for (int ks = 0; ks < 2; ++ks) {
                kbh[j][ks] = *(const bf16x8*)&Ksh[j * 16 + fr][ks * 32 + g * 8];
                kbl[j][ks] = *(const bf16x8*)&Ksl[j * 16 + fr][ks * 32 + g * 8];
            }
        f32x4 s[3][2] = {};
        #pragma unroll
        for (int i = 0; i < 3; ++i)
            #pragma unroll
            for (int j = 0; j < 2; ++j)
                #pragma unroll
                for (int ks = 0; ks < 2; ++ks) {
                    s[i][j] = __builtin_amdgcn_mfma_f32_16x16x32_bf16(qh[i][ks], kbh[j][ks], s[i][j], 0, 0, 0);
                    s[i][j] = __builtin_amdgcn_mfma_f32_16x16x32_bf16(qh[i][ks], kbl[j][ks], s[i][j], 0, 0, 0);
                    s[i][j] = __builtin_amdgcn_mfma_f32_16x16x32_bf16(ql[i][ks], kbh[j][ks], s[i][j], 0, 0, 0);
                }
        #pragma unroll
        for (int i = 0; i < 3; ++i) {
            float tmax[4], mn[4], corr[4], psum[4];
            #pragma unroll
            for (int r = 0; r < 4; ++r) tmax[r] = fmaxf(s[i][0][r], s[i][1][r]);
            #pragma unroll
            for (int off = 8; off; off >>= 1)
                #pragma unroll
                for (int r = 0; r < 4; ++r) tmax[r] = fmaxf(tmax[r], __shfl_xor(tmax[r], off));
            float p0[4], p1[4];
            #pragma unroll
            for (int r = 0; r < 4; ++r) {
                mn[r] = fmaxf(m[i][r], tmax[r]);
                corr[r] = expf(m[i][r] - mn[r]);
                p0[r] = expf(s[i][0][r] - mn[r]);
                p1[r] = expf(s[i][1][r] - mn[r]);
                psum[r] = p0[r] + p1[r];
                m[i][r] = mn[r];
            }
            #pragma unroll
            for (int off = 8; off; off >>= 1)
                #pragma unroll
                for (int r = 0; r < 4; ++r) psum[r] += __shfl_xor(psum[r], off);
            #pragma unroll
            for (int r = 0; r < 4; ++r) l[i][r] = l[i][r] * corr[r] + psum[r];
            #pragma unroll
            for (int dj = 0; dj < 4; ++dj)
                #pragma unroll
                for (int r = 0; r < 4; ++r) oacc[i][dj][r] *= corr[r];
            #pragma unroll
            for (int r = 0; r < 4; ++r) {
                int rl = i * 16 + g * 4 + r;
                u16 h0 = bf16_rne(p0[r]);
                Psh[wid][rl][fr]      = h0;
                Psl[wid][rl][fr]      = bf16_rne(p0[r] - bf16_f32(h0));
                u16 h1 = bf16_rne(p1[r]);
                Psh[wid][rl][16 + fr] = h1;
                Psl[wid][rl][16 + fr] = bf16_rne(p1[r] - bf16_f32(h1));
            }
        }
        bf16x8 pah[3], pal[3];
        #pragma unroll
        for (int i = 0; i < 3; ++i) {
            pah[i] = *(const bf16x8*)&Psh[wid][i * 16 + fr][g * 8];
            pal[i] = *(const bf16x8*)&Psl[wid][i * 16 + fr][g * 8];
        }
        bf16x8 vbh[4], vbl[4];
        #pragma unroll
        for (int dj = 0; dj < 4; ++dj) {
            vbh[dj] = *(const bf16x8*)&Vsh[dj * 16 + fr][g * 8];
            vbl[dj] = *(const bf16x8*)&Vsl[dj * 16 + fr][g * 8];
        }
        #pragma unroll
        for (int i = 0; i < 3; ++i)
            #pragma unroll
            for (int dj = 0; dj < 4; ++dj) {
                oacc[i][dj] = __builtin_amdgcn_mfma_f32_16x16x32_bf16(pah[i], vbh[dj], oacc[i][dj], 0, 0, 0);
                oacc[i][dj] = __builtin_amdgcn_mfma_f32_16x16x32_bf16(pah[i], vbl[dj], oacc[i][dj], 0, 0, 0);
                oacc[i][dj] = __builtin_amdgcn_mfma_f32_16x16x32_bf16(pal[i], vbh[dj], oacc[i][dj], 0, 0, 0);
            }
    }
    #pragma unroll
    for (int i = 0; i < 3; ++i) {
        #pragma unroll
        for (int r = 0; r < 4; ++r) {
            int row = wid * 48 + i * 16 + g * 4 + r;
            float invl = 1.0f / l[i][r];
            #pragma unroll
            for (int dj = 0; dj < 4; ++dj) {
                float v = oacc[i][dj][r] * invl;
                size_t ob = (rowbase + row) * 512 + h * 64 + dj * 16 + fr;
                u16 hh = bf16_rne(v);
                Oh[ob] = hh;
                Ol[ob] = bf16_rne(v - bf16_f32(hh));
            }
        }
    }
}

extern "C" void kernel_launch(void* const* d_in, const int* in_sizes, int n_in,
                              void* d_out, int out_size, void* d_ws, size_t ws_size,
                              hipStream_t stream) {
    (void)in_sizes; (void)n_in; (void)out_size; (void)ws_size;
    const float* video   = (const float*)d_in[0];
    const float* patch_w = (const float*)d_in[1];
    const float* patch_b = (const float*)d_in[2];
    const float* ln_t_g  = (const float*)d_in[3];
    const float* ln_t_b  = (const float*)d_in[4];
    const float* ln_s_g  = (const float*)d_in[5];
    const float* ln_s_b  = (const float*)d_in[6];
    const float* ln_f_g  = (const float*)d_in[7];
    const float* ln_f_b  = (const float*)d_in[8];
    const float* qkv_t   = (const float*)d_in[9];
    const float* out_t_w = (const float*)d_in[10];
    const float* out_t_b = (const float*)d_in[11];
    const float* qkv_s   = (const float*)d_in[12];
    const float* out_s_w = (const float*)d_in[13];
    const float* out_s_b = (const float*)d_in[14];
    const float* ff_w1   = (const float*)d_in[15];
    const float* ff_b1   = (const float*)d_in[16];
    const float* ff_w2   = (const float*)d_in[17];
    const float* ff_b2   = (const float*)d_in[18];

    float* x = (float*)d_out;                   // [12288][512] residual stream

    // ---- workspace layout (~104.5 MB) ----
    u16* wqt_h = (u16*)d_ws;                    // qkv_t^T pair [1536][512]
    u16* wqt_l = wqt_h + 1536 * 512;
    u16* wot_h = wqt_l + 1536 * 512;            // out_t^T pair [512][512]
    u16* wot_l = wot_h + 512 * 512;
    u16* wqs_h = wot_l + 512 * 512;
    u16* wqs_l = wqs_h + 1536 * 512;
    u16* wos_h = wqs_l + 1536 * 512;
    u16* wos_l = wos_h + 512 * 512;
    u16* wpt_h = wos_l + 512 * 512;             // patch_w^T pair [512][192]
    u16* wpt_l = wpt_h + 512 * PATCH_K;
    u16* y_h   = wpt_l + 512 * PATCH_K;         // activation pair [12288][512]; o aliases y
    u16* y_l   = y_h + (size_t)ROWS * DIM_;
    float* big2 = (float*)(y_l + (size_t)ROWS * DIM_);  // 75.5 MB multi-use region
    float* qkv  = big2;                                  // attn phase: [12288][1536] fp32
    u16* vp_h = (u16*)big2;                              // patch pre pair [12288][192]
    u16* vp_l = vp_h + (size_t)ROWS * PATCH_K;
    u16* h2    = (u16*)big2;                             // FF phase: [12288][2048] single plane
    u16* f1t_h = h2 + (size_t)ROWS * FFH_;               // ff_w1^T pair [4096][512]
    u16* f1t_l = f1t_h + 4096 * 512;
    u16* f2t_h = f1t_l + 4096 * 512;                     // ff_w2^T pair [512][2048]
    u16* f2t_l = f2t_h + 512 * FFH_;
    float* fsin = (float*)((char*)big2 + (size_t)ROWS * 1536 * 4);
    float* fcos = fsin + F_ * 64;
    float* isin = fcos + F_ * 64;
    float* icos = isin + N_ * 64;
    u16* o_h = y_h;
    u16* o_l = y_l;

    rope_tables<<<2, 256, 0, stream>>>(fsin, fcos, isin, icos);

    // ---- patch embed ----
    convert_wt<<<dim3(DIM_ / 32, PATCH_K / 32), 256, 0, stream>>>(patch_w, wpt_h, wpt_l, PATCH_K, DIM_);
    rearrange_video_p<<<(ROWS * PATCH_K + 255) / 256, 256, 0, stream>>>(video, vp_h, vp_l);
    gemm_n64<0, 1><<<dim3(DIM_ / 64, ROWS / 128), 256, 0, stream>>>(
        vp_h, vp_l, wpt_h, wpt_l, patch_b, x, ROWS, DIM_, PATCH_K);

    for (int l = 0; l < 4; ++l) {
        convert_wt<<<dim3(1536 / 32, DIM_ / 32), 256, 0, stream>>>(
            qkv_t + (size_t)l * DIM_ * 1536, wqt_h, wqt_l, DIM_, 1536);
        convert_wt<<<dim3(DIM_ / 32, DIM_ / 32), 256, 0, stream>>>(
            out_t_w + (size_t)l * DIM_ * DIM_, wot_h, wot_l, DIM_, DIM_);
        convert_wt<<<dim3(1536 / 32, DIM_ / 32), 256, 0, stream>>>(
            qkv_s + (size_t)l * DIM_ * 1536, wqs_h, wqs_l, DIM_, 1536);
        convert_wt<<<dim3(DIM_ / 32, DIM_ / 32), 256, 0, stream>>>(
            out_s_w + (size_t)l * DIM_ * DIM_, wos_h, wos_l, DIM_, DIM_);

        // ---- time attention ----
        layernorm_p<<<ROWS, 64, 0, stream>>>(x, ln_t_g + l * DIM_, ln_t_b + l * DIM_, y_h, y_l);
        gemm_mfma3<0><<<dim3(1536 / 128, ROWS / 128), 256, 0, stream>>>(
            y_h, y_l, wqt_h, wqt_l, nullptr, qkv, ROWS, 1536, DIM_);
        attn_time<<<B_ * HEADS_ * N_, 64, 0, stream>>>(qkv, fsin, fcos, o_h, o_l);
        gemm_n64<1, 1><<<dim3(DIM_ / 64, ROWS / 128), 256, 0, stream>>>(
            o_h, o_l, wot_h, wot_l, out_t_b + l * DIM_, x, ROWS, DIM_, DIM_);

        // ---- spatial attention (MFMA flash) ----
        layernorm_p<<<ROWS, 64, 0, stream>>>(x, ln_s_g + l * DIM_, ln_s_b + l * DIM_, y_h, y_l);
        gemm_mfma3<0><<<dim3(1536 / 128, ROWS / 128), 256, 0, stream>>>(
            y_h, y_l, wqs_h, wqs_l, nullptr, qkv, ROWS, 1536, DIM_);
        attn_space_mfma<<<B_ * HEADS_ * F_, 256, 0, stream>>>(qkv, isin, icos, o_h, o_l);
        gemm_n64<1, 1><<<dim3(DIM_ / 64, ROWS / 128), 256, 0, stream>>>(
            o_h, o_l, wos_h, wos_l, out_s_b + l * DIM_, x, ROWS, DIM_, DIM_);

        // ---- FF with fused GLU (A = LN hi plane only; split-2) ----
        convert_wt<<<dim3(4096 / 32, DIM_ / 32), 256, 0, stream>>>(
            ff_w1 + (size_t)l * DIM_ * 2 * FFH_, f1t_h, f1t_l, DIM_, 4096);
        convert_wt<<<dim3(DIM_ / 32, FFH_ / 32), 256, 0, stream>>>(
            ff_w2 + (size_t)l * FFH_ * DIM_, f2t_h, f2t_l, FFH_, DIM_);
        layernorm_p<<<ROWS, 64, 0, stream>>>(x, ln_f_g + l * DIM_, ln_f_b + l * DIM_, y_h, nullptr);
        gemm_glu3<<<dim3(FFH_ / 64, ROWS / 128), 256, 0, stream>>>(
            y_h, f1t_h, f1t_l, ff_b1 + l * 2 * FFH_, h2);
        gemm_n64<1, 0><<<dim3(DIM_ / 64, ROWS / 128), 256, 0, stream>>>(
            h2, nullptr, f2t_h, f2t_l, ff_b2 + l * DIM_, x, ROWS, DIM_, FFH_);
    }
}